// Round 2
// baseline (334.798 us; speedup 1.0000x reference)
//
#include <hip/hip_runtime.h>
#include <stdint.h>

#define EMB 1024
#define NHEADS 16
#define HDIM 64
#define BB 4
#define SS 2048
#define MR (BB*SS)   // 8192 rows

typedef float f32x4 __attribute__((ext_vector_type(4)));
typedef short s16x8 __attribute__((ext_vector_type(8)));
typedef unsigned short u16;
typedef u16 u16x8 __attribute__((ext_vector_type(8)));

__device__ __forceinline__ float bf2f(u16 h){
  union{uint32_t u;float f;} v; v.u = ((uint32_t)h)<<16; return v.f;
}
__device__ __forceinline__ u16 f2bf(float f){
  union{float f;uint32_t u;} v; v.f=f; uint32_t u=v.u;
  return (u16)((u + 0x7FFFu + ((u>>16)&1u)) >> 16);   // RNE
}

// async global->LDS, 16B per lane. LDS dest = wave-uniform base + lane*16.
__device__ __forceinline__ void stage16(const void* g, void* lds_base){
  __builtin_amdgcn_global_load_lds(
      (__attribute__((address_space(1))) void*)(g),
      (__attribute__((address_space(3))) void*)(lds_base),
      16, 0, 0);
}

// ---------------- rope table: [s][j] cos/sin, j = pair index 0..31 ----------------
__global__ void k_tables(float2* __restrict__ tab){
  int idx = blockIdx.x*256 + threadIdx.x;
  if (idx >= SS*32) return;
  int s = idx >> 5, j = idx & 31;
  double ntk = (double)SS / 1024.0;                        // seq_len / BLOCK_SIZE
  double invf = pow(10000.0, -((double)(2*j))/(64.0*ntk)); // 10000^(-i/(D*ntk))
  double p = (double)s / 1024.0;
  double scal = 1.0 / sqrt(1.0 + p*p);                     // yarn scaling (alpha=1)
  double th = (double)s * invf * scal;
  tab[idx] = make_float2((float)cos(th), (float)sin(th));
}

// ---------------- f32 -> bf16, 4/thread ----------------
__global__ void k_cvt(const float* __restrict__ in, u16* __restrict__ out, int n){
  int i = (blockIdx.x*256 + threadIdx.x)*4;
  if (i >= n) return;
  float4 v = *(const float4*)(in + i);
  union{u16 a[4]; uint64_t q;} pk;
  pk.a[0]=f2bf(v.x); pk.a[1]=f2bf(v.y); pk.a[2]=f2bf(v.z); pk.a[3]=f2bf(v.w);
  *(uint64_t*)(out + i) = pk.q;
}

// ---------------- in-place RoPE on q and k (bf16 [B,S,E]) ----------------
__global__ void k_rope(u16* __restrict__ q, u16* __restrict__ kk,
                       const float2* __restrict__ tab){
  const size_t nper = (size_t)MR*EMB/8;
  size_t t = (size_t)blockIdx.x*256 + threadIdx.x;
  u16* buf = q;
  if (t >= nper){ buf = kk; t -= nper; }
  size_t base = t*8;
  int e = (int)(base & (EMB-1));
  int d = e & 63;
  int s = (int)((base >> 10) & (SS-1));
  const float2* tr = tab + s*32 + (d>>1);
  u16x8 v = *(const u16x8*)(buf + base);
  u16x8 o;
  #pragma unroll
  for (int p=0;p<4;p++){
    float2 cs = tr[p];
    float ev = bf2f(v[2*p]), od = bf2f(v[2*p+1]);
    o[2*p]   = f2bf(ev*cs.x - od*cs.y);
    o[2*p+1] = f2bf(ev*cs.y + od*cs.x);
  }
  *(u16x8*)(buf + base) = o;
}

// ---------------- V transpose: [B,S,E] -> vt[bh][d][s] ----------------
__global__ void k_vt(const u16* __restrict__ v, u16* __restrict__ vt){
  __shared__ u16 tl[64][80];   // pad; 160B row stride keeps 16B alignment
  int bh = blockIdx.x, s0 = blockIdx.y*64;
  int b = bh>>4, h = bh&15;
  int tid = threadIdx.x;
  #pragma unroll
  for (int p=0;p<2;p++){
    int c = p*256+tid, s = c>>3, d0 = (c&7)*8;
    u16x8 x = *(const u16x8*)(v + ((size_t)(b*SS + s0+s))*EMB + h*64 + d0);
    *(u16x8*)&tl[s][d0] = x;
  }
  __syncthreads();
  #pragma unroll
  for (int p=0;p<2;p++){
    int c = p*256+tid, d = c>>3, sc = (c&7)*8;
    u16x8 x;
    #pragma unroll
    for (int i=0;i<8;i++) x[i] = tl[sc+i][d];
    *(u16x8*)(vt + ((size_t)bh*64 + d)*SS + s0 + sc) = x;
  }
}

// ---------------- bt-GEMM (m97 structure): C[m][n] = sum_k A[m][k]*B[n][k] ----------------
// MODE 0: 3 outputs (z selects W/C), bf16 out. MODE 1: f32 out + bias.
template<int MODE>
__global__ __launch_bounds__(256) void k_gemm(
    const u16* __restrict__ A,
    const u16* __restrict__ B0, const u16* __restrict__ B1, const u16* __restrict__ B2,
    u16* __restrict__ C0, u16* __restrict__ C1, u16* __restrict__ C2,
    const float* __restrict__ bias, float* __restrict__ Cf)
{
  constexpr int K = EMB;
  __shared__ u16 As[128][32];
  __shared__ u16 Bs[128][32];
  const int tid = threadIdx.x, lane = tid & 63, wave = tid >> 6;
  const int wr = wave >> 1, wc = wave & 1;
  const int m0 = blockIdx.x*128, n0 = blockIdx.y*128;
  const u16* Bm = (MODE==1) ? B0 : (blockIdx.z==0 ? B0 : (blockIdx.z==1 ? B1 : B2));
  u16* Cb = (blockIdx.z==0 ? C0 : (blockIdx.z==1 ? C1 : C2));

  f32x4 acc[4][4];
  #pragma unroll
  for (int i=0;i<4;i++)
    #pragma unroll
    for (int j=0;j<4;j++)
      #pragma unroll
      for (int r=0;r<4;r++) acc[i][j][r] = 0.f;

  const int cl = lane & 15, kq = (lane>>4)*8, rg = lane>>4;
  char* AsB = (char*)&As[0][0];
  char* BsB = (char*)&Bs[0][0];
  const int wbase = wave*1024;

  for (int k0 = 0; k0 < K; k0 += 32) {
    __syncthreads();
    #pragma unroll
    for (int p=0;p<2;p++){
      int c = p*256 + tid;
      int row = c>>2, sub = c&3;
      stage16(A  + (size_t)(m0+row)*K + k0 + sub*8, AsB + p*4096 + wbase);
      stage16(Bm + (size_t)(n0+row)*K + k0 + sub*8, BsB + p*4096 + wbase);
    }
    __syncthreads();
    s16x8 a[4], b[4];
    #pragma unroll
    for (int i=0;i<4;i++){
      a[i] = *(const s16x8*)&As[wr*64 + i*16 + cl][kq];
      b[i] = *(const s16x8*)&Bs[wc*64 + i*16 + cl][kq];
    }
    #pragma unroll
    for (int i=0;i<4;i++)
      #pragma unroll
      for (int j=0;j<4;j++)
        acc[i][j] = __builtin_amdgcn_mfma_f32_16x16x32_bf16(a[i], b[j], acc[i][j], 0, 0, 0);
  }

  // C layout: col = lane&15, row = (lane>>4)*4 + r  [m89]
  #pragma unroll
  for (int i=0;i<4;i++)
    #pragma unroll
    for (int j=0;j<4;j++){
      int col = n0 + wc*64 + j*16 + cl;
      #pragma unroll
      for (int r=0;r<4;r++){
        int row = m0 + wr*64 + i*16 + rg*4 + r;
        if constexpr (MODE==0){
          Cb[(size_t)row*EMB + col] = f2bf(acc[i][j][r]);
        } else {
          Cf[(size_t)row*EMB + col] = acc[i][j][r] + bias[col];
        }
      }
    }
}

// ---------------- flash attention: 1 block per (bh, 128-row q tile) ----------------
// Output written in the reference's scrambled-reshape layout:
//   ob[b][h*128 + (q>>4)][(q&15)*64 + d]  (= [B,H,S,D].reshape(B,S,E) with NO transpose)
__global__ __launch_bounds__(256) void k_attn(
    const u16* __restrict__ q, const u16* __restrict__ k,
    const u16* __restrict__ vt, u16* __restrict__ o)
{
  __shared__ u16 Qs[128][64];   // 16KB
  __shared__ u16 Ks[64][64];    // 8KB
  __shared__ u16 Vs[64][64];    // 8KB (d-major: Vs[d][kv])
  __shared__ u16 Ps[4][32][64]; // 16KB per-wave P staging

  const int tid = threadIdx.x, lane = tid&63, wave = tid>>6;
  const int cl = lane&15, rg = lane>>4, kq = rg*8;
  const int bh = blockIdx.x;
  const int q0 = blockIdx.y*128;
  const int b = bh>>4, h = bh&15;
  const size_t qk0 = (size_t)b*SS*EMB + h*64;
  const u16* vtb = vt + (size_t)bh*64*SS;
  const int wbase = wave*1024;

  // stage Q tile (16KB)
  #pragma unroll
  for (int p=0;p<4;p++){
    int c = p*256+tid, row = c>>3, d0 = (c&7)*8;
    stage16(q + qk0 + (size_t)(q0+row)*EMB + d0, (char*)Qs + p*4096 + wbase);
  }
  __syncthreads();

  // hoist Q fragments
  s16x8 qf[2][2];
  #pragma unroll
  for (int mi=0;mi<2;mi++)
    #pragma unroll
    for (int kk2=0;kk2<2;kk2++)
      qf[mi][kk2] = *(const s16x8*)&Qs[wave*32 + mi*16 + cl][kk2*32 + kq];

  float mrun[2][4], lrun[2][4];
  f32x4 oacc[2][4];
  #pragma unroll
  for (int i=0;i<2;i++)
    #pragma unroll
    for (int r=0;r<4;r++){ mrun[i][r] = -1e30f; lrun[i][r] = 0.f; }
  #pragma unroll
  for (int i=0;i<2;i++)
    #pragma unroll
    for (int j=0;j<4;j++)
      #pragma unroll
      for (int r=0;r<4;r++) oacc[i][j][r] = 0.f;

  const int rowbase = q0 + wave*32;
  const int nt = (q0 + 128)/64;
  const float SCL = 0.125f * 1.44269504088896340736f;  // 1/sqrt(64) * log2(e)

  for (int t=0;t<nt;t++){
    int kv0 = t*64;
    __syncthreads();
    #pragma unroll
    for (int p=0;p<2;p++){
      int c = p*256+tid, row = c>>3, d0 = (c&7)*8;
      stage16(k + qk0 + (size_t)(kv0+row)*EMB + d0, (char*)Ks + p*4096 + wbase);
      stage16(vtb + (size_t)row*SS + kv0 + d0,      (char*)Vs + p*4096 + wbase);
    }
    __syncthreads();

    if (kv0 <= rowbase + 31) {            // wave has at least one unmasked col
      f32x4 sc[2][4];
      #pragma unroll
      for (int i=0;i<2;i++)
        #pragma unroll
        for (int j=0;j<4;j++)
          #pragma unroll
          for (int r=0;r<4;r++) sc[i][j][r] = 0.f;

      #pragma unroll
      for (int kk2=0;kk2<2;kk2++){
        s16x8 kf[4];
        #pragma unroll
        for (int nj=0;nj<4;nj++) kf[nj] = *(const s16x8*)&Ks[nj*16+cl][kk2*32+kq];
        #pragma unroll
        for (int mi=0;mi<2;mi++)
          #pragma unroll
          for (int nj=0;nj<4;nj++)
            sc[mi][nj] = __builtin_amdgcn_mfma_f32_16x16x32_bf16(qf[mi][kk2], kf[nj], sc[mi][nj], 0,0,0);
      }

      const bool full = (kv0 + 63) <= rowbase;   // whole tile unmasked for this wave
      #pragma unroll
      for (int mi=0;mi<2;mi++){
        #pragma unroll
        for (int r=0;r<4;r++){
          int row = rowbase + mi*16 + rg*4 + r;
          float mx = -1e30f;
          #pragma unroll
          for (int nj=0;nj<4;nj++){
            float vv = sc[mi][nj][r]*SCL;
            if (!full){ int col = kv0 + nj*16 + cl; vv = (col<=row) ? vv : -1e30f; }
            sc[mi][nj][r] = vv; mx = fmaxf(mx, vv);
          }
          #pragma unroll
          for (int off=1;off<16;off<<=1) mx = fmaxf(mx, __shfl_xor(mx, off, 64));
          float mn = fmaxf(mrun[mi][r], mx);
          float corr = exp2f(mrun[mi][r] - mn);
          mrun[mi][r] = mn;
          float rs = 0.f;
          #pragma unroll
          for (int nj=0;nj<4;nj++){
            float pv = exp2f(sc[mi][nj][r] - mn);
            sc[mi][nj][r] = pv; rs += pv;
          }
          #pragma unroll
          for (int off=1;off<16;off<<=1) rs += __shfl_xor(rs, off, 64);
          lrun[mi][r] = lrun[mi][r]*corr + rs;
          #pragma unroll
          for (int nj=0;nj<4;nj++) oacc[mi][nj][r] *= corr;
        }
      }

      // P (C-layout) -> LDS bf16
      #pragma unroll
      for (int mi=0;mi<2;mi++)
        #pragma unroll
        for (int nj=0;nj<4;nj++)
          #pragma unroll
          for (int r=0;r<4;r++)
            Ps[wave][mi*16 + rg*4 + r][nj*16 + cl] = f2bf(sc[mi][nj][r]);

      // PV: O += P @ V
      #pragma unroll
      for (int kk2=0;kk2<2;kk2++){
        s16x8 pf[2], vf[4];
        pf[0] = *(const s16x8*)&Ps[wave][cl][kk2*32+kq];
        pf[1] = *(const s16x8*)&Ps[wave][16+cl][kk2*32+kq];
        #pragma unroll
        for (int nj=0;nj<4;nj++) vf[nj] = *(const s16x8*)&Vs[nj*16+cl][kk2*32+kq];
        #pragma unroll
        for (int mi=0;mi<2;mi++)
          #pragma unroll
          for (int nj=0;nj<4;nj++)
            oacc[mi][nj] = __builtin_amdgcn_mfma_f32_16x16x32_bf16(pf[mi], vf[nj], oacc[mi][nj], 0,0,0);
      }
    }
  }

  // epilogue in SCRAMBLED reference layout:
  // o[b][h*128 + (q>>4)][(q&15)*64 + d],  d = nj*16+cl, q = rowbase+mi*16+rg*4+r
  #pragma unroll
  for (int mi=0;mi<2;mi++)
    #pragma unroll
    for (int nj=0;nj<4;nj++)
      #pragma unroll
      for (int r=0;r<4;r++){
        int row = rowbase + mi*16 + rg*4 + r;
        float val = oacc[mi][nj][r] / lrun[mi][r];
        int sp = h*128 + (row>>4);
        int ep = (row&15)*64 + nj*16 + cl;
        o[((size_t)b*SS + sp)*EMB + ep] = f2bf(val);
      }
}

// ---------------- launch ----------------
extern "C" void kernel_launch(void* const* d_in, const int* in_sizes, int n_in,
                              void* d_out, int out_size, void* d_ws, size_t ws_size,
                              hipStream_t stream)
{
  const float* x  = (const float*)d_in[0];
  const float* Wq = (const float*)d_in[1];
  const float* Wk = (const float*)d_in[2];
  const float* Wv = (const float*)d_in[3];
  const float* Wp = (const float*)d_in[4];
  const float* bp = (const float*)d_in[5];
  float* out = (float*)d_out;

  char* ws = (char*)d_ws;
  const size_t XE = (size_t)MR*EMB*2;      // 16MB
  const size_t WE = (size_t)EMB*EMB*2;     // 2MB
  u16* xb  = (u16*)ws; ws += XE;           // x bf16; reused as vt after GEMM1
  u16* wqb = (u16*)ws; ws += WE;
  u16* wkb = (u16*)ws; ws += WE;
  u16* wvb = (u16*)ws; ws += WE;
  u16* wpb = (u16*)ws; ws += WE;
  u16* qb  = (u16*)ws; ws += XE;
  u16* kb  = (u16*)ws; ws += XE;
  u16* vb  = (u16*)ws; ws += XE;           // v bf16; reused as attn-out after k_vt
  float2* tab = (float2*)ws; ws += (size_t)SS*32*sizeof(float2);
  u16* vtb = xb;                           // alias: x dead after GEMM1
  u16* ob  = vb;                           // alias: v dead after k_vt

  k_tables<<<(SS*32+255)/256, 256, 0, stream>>>(tab);
  k_cvt<<<(MR*EMB/4+255)/256, 256, 0, stream>>>(x,  xb,  MR*EMB);
  k_cvt<<<(EMB*EMB/4+255)/256, 256, 0, stream>>>(Wq, wqb, EMB*EMB);
  k_cvt<<<(EMB*EMB/4+255)/256, 256, 0, stream>>>(Wk, wkb, EMB*EMB);
  k_cvt<<<(EMB*EMB/4+255)/256, 256, 0, stream>>>(Wv, wvb, EMB*EMB);
  k_cvt<<<(EMB*EMB/4+255)/256, 256, 0, stream>>>(Wp, wpb, EMB*EMB);

  dim3 g1(MR/128, EMB/128, 3);
  k_gemm<0><<<g1, 256, 0, stream>>>(xb, wqb, wkb, wvb, qb, kb, vb, nullptr, nullptr);

  k_rope<<<(2*(MR*EMB/8))/256, 256, 0, stream>>>(qb, kb, tab);
  k_vt<<<dim3(BB*NHEADS, SS/64), 256, 0, stream>>>(vb, vtb);
  k_attn<<<dim3(BB*NHEADS, SS/128), 256, 0, stream>>>(qb, kb, vtb, ob);

  dim3 g2(MR/128, EMB/128, 1);
  k_gemm<1><<<g2, 256, 0, stream>>>(ob, wpb, nullptr, nullptr, nullptr, nullptr, nullptr, bp, out);
}

// Round 3
// 275.256 us; speedup vs baseline: 1.2163x; 1.2163x over previous
//
#include <hip/hip_runtime.h>
#include <stdint.h>

#define EMB 1024
#define NHEADS 16
#define HDIM 64
#define BB 4
#define SS 2048
#define MR (BB*SS)   // 8192 rows

typedef float f32x4 __attribute__((ext_vector_type(4)));
typedef short s16x8 __attribute__((ext_vector_type(8)));
typedef unsigned short u16;
typedef u16 u16x8 __attribute__((ext_vector_type(8)));

__device__ __forceinline__ float bf2f(u16 h){
  union{uint32_t u;float f;} v; v.u = ((uint32_t)h)<<16; return v.f;
}
__device__ __forceinline__ u16 f2bf(float f){
  union{float f;uint32_t u;} v; v.f=f; uint32_t u=v.u;
  return (u16)((u + 0x7FFFu + ((u>>16)&1u)) >> 16);   // RNE
}

// async global->LDS, 16B per lane. LDS dest = wave-uniform base + lane*16.
__device__ __forceinline__ void stage16(const void* g, void* lds_base){
  __builtin_amdgcn_global_load_lds(
      (__attribute__((address_space(1))) void*)(g),
      (__attribute__((address_space(3))) void*)(lds_base),
      16, 0, 0);
}

// ---------------- rope table: [s][j] cos/sin, j = pair index 0..31 ----------------
__global__ void k_tables(float2* __restrict__ tab){
  int idx = blockIdx.x*256 + threadIdx.x;
  if (idx >= SS*32) return;
  int s = idx >> 5, j = idx & 31;
  double ntk = (double)SS / 1024.0;                        // seq_len / BLOCK_SIZE
  double invf = pow(10000.0, -((double)(2*j))/(64.0*ntk)); // 10000^(-i/(D*ntk))
  double p = (double)s / 1024.0;
  double scal = 1.0 / sqrt(1.0 + p*p);                     // yarn scaling (alpha=1)
  double th = (double)s * invf * scal;
  tab[idx] = make_float2((float)cos(th), (float)sin(th));
}

// ---------------- f32 -> bf16, 4/thread ----------------
__global__ void k_cvt(const float* __restrict__ in, u16* __restrict__ out, int n){
  int i = (blockIdx.x*256 + threadIdx.x)*4;
  if (i >= n) return;
  float4 v = *(const float4*)(in + i);
  union{u16 a[4]; uint64_t q;} pk;
  pk.a[0]=f2bf(v.x); pk.a[1]=f2bf(v.y); pk.a[2]=f2bf(v.z); pk.a[3]=f2bf(v.w);
  *(uint64_t*)(out + i) = pk.q;
}

// ---------------- in-place RoPE on q and k (bf16 [B,S,E]) ----------------
__global__ void k_rope(u16* __restrict__ q, u16* __restrict__ kk,
                       const float2* __restrict__ tab){
  const size_t nper = (size_t)MR*EMB/8;
  size_t t = (size_t)blockIdx.x*256 + threadIdx.x;
  u16* buf = q;
  if (t >= nper){ buf = kk; t -= nper; }
  size_t base = t*8;
  int e = (int)(base & (EMB-1));
  int d = e & 63;
  int s = (int)((base >> 10) & (SS-1));
  const float2* tr = tab + s*32 + (d>>1);
  u16x8 v = *(const u16x8*)(buf + base);
  u16x8 o;
  #pragma unroll
  for (int p=0;p<4;p++){
    float2 cs = tr[p];
    float ev = bf2f(v[2*p]), od = bf2f(v[2*p+1]);
    o[2*p]   = f2bf(ev*cs.x - od*cs.y);
    o[2*p+1] = f2bf(ev*cs.y + od*cs.x);
  }
  *(u16x8*)(buf + base) = o;
}

// ---------------- V transpose: [B,S,E] -> vt[bh][d][s] ----------------
__global__ void k_vt(const u16* __restrict__ v, u16* __restrict__ vt){
  __shared__ u16 tl[64][80];   // pad; 160B row stride keeps 16B alignment
  int bh = blockIdx.x, s0 = blockIdx.y*64;
  int b = bh>>4, h = bh&15;
  int tid = threadIdx.x;
  #pragma unroll
  for (int p=0;p<2;p++){
    int c = p*256+tid, s = c>>3, d0 = (c&7)*8;
    u16x8 x = *(const u16x8*)(v + ((size_t)(b*SS + s0+s))*EMB + h*64 + d0);
    *(u16x8*)&tl[s][d0] = x;
  }
  __syncthreads();
  #pragma unroll
  for (int p=0;p<2;p++){
    int c = p*256+tid, d = c>>3, sc = (c&7)*8;
    u16x8 x;
    #pragma unroll
    for (int i=0;i<8;i++) x[i] = tl[sc+i][d];
    *(u16x8*)(vt + ((size_t)bh*64 + d)*SS + s0 + sc) = x;
  }
}

// ---------------- bt-GEMM (m97 structure): C[m][n] = sum_k A[m][k]*B[n][k] ----------------
// MODE 0: 3 outputs (z selects W/C), bf16 out. MODE 1: f32 out + bias.
template<int MODE>
__global__ __launch_bounds__(256) void k_gemm(
    const u16* __restrict__ A,
    const u16* __restrict__ B0, const u16* __restrict__ B1, const u16* __restrict__ B2,
    u16* __restrict__ C0, u16* __restrict__ C1, u16* __restrict__ C2,
    const float* __restrict__ bias, float* __restrict__ Cf)
{
  constexpr int K = EMB;
  __shared__ u16 As[128][32];
  __shared__ u16 Bs[128][32];
  const int tid = threadIdx.x, lane = tid & 63, wave = tid >> 6;
  const int wr = wave >> 1, wc = wave & 1;
  const int m0 = blockIdx.x*128, n0 = blockIdx.y*128;
  const u16* Bm = (MODE==1) ? B0 : (blockIdx.z==0 ? B0 : (blockIdx.z==1 ? B1 : B2));
  u16* Cb = (blockIdx.z==0 ? C0 : (blockIdx.z==1 ? C1 : C2));

  f32x4 acc[4][4];
  #pragma unroll
  for (int i=0;i<4;i++)
    #pragma unroll
    for (int j=0;j<4;j++)
      #pragma unroll
      for (int r=0;r<4;r++) acc[i][j][r] = 0.f;

  const int cl = lane & 15, kq = (lane>>4)*8, rg = lane>>4;
  char* AsB = (char*)&As[0][0];
  char* BsB = (char*)&Bs[0][0];
  const int wbase = wave*1024;

  for (int k0 = 0; k0 < K; k0 += 32) {
    __syncthreads();
    #pragma unroll
    for (int p=0;p<2;p++){
      int c = p*256 + tid;
      int row = c>>2, sub = c&3;
      stage16(A  + (size_t)(m0+row)*K + k0 + sub*8, AsB + p*4096 + wbase);
      stage16(Bm + (size_t)(n0+row)*K + k0 + sub*8, BsB + p*4096 + wbase);
    }
    __syncthreads();
    s16x8 a[4], b[4];
    #pragma unroll
    for (int i=0;i<4;i++){
      a[i] = *(const s16x8*)&As[wr*64 + i*16 + cl][kq];
      b[i] = *(const s16x8*)&Bs[wc*64 + i*16 + cl][kq];
    }
    #pragma unroll
    for (int i=0;i<4;i++)
      #pragma unroll
      for (int j=0;j<4;j++)
        acc[i][j] = __builtin_amdgcn_mfma_f32_16x16x32_bf16(a[i], b[j], acc[i][j], 0, 0, 0);
  }

  // C layout: col = lane&15, row = (lane>>4)*4 + r  [m89]
  #pragma unroll
  for (int i=0;i<4;i++)
    #pragma unroll
    for (int j=0;j<4;j++){
      int col = n0 + wc*64 + j*16 + cl;
      #pragma unroll
      for (int r=0;r<4;r++){
        int row = m0 + wr*64 + i*16 + rg*4 + r;
        if constexpr (MODE==0){
          Cb[(size_t)row*EMB + col] = f2bf(acc[i][j][r]);
        } else {
          Cf[(size_t)row*EMB + col] = acc[i][j][r] + bias[col];
        }
      }
    }
}

// ---------------- flash attention: 1 block per (bh, 128-row q tile) ----------------
// All LDS tiles XOR-swizzled (T2): 64-elem (128B) rows, 16B chunk j of row r holds
// global chunk j^(r&7). Staged tiles pre-swizzle the GLOBAL source (rule #21);
// Ps swizzles write+read directly. Ps aliases Qs (dead after Q-frag hoist): LDS 32KB.
// Output in the reference's scrambled-reshape layout:
//   ob[b][h*128 + (q>>4)][(q&15)*64 + d]
__global__ __launch_bounds__(256) void k_attn(
    const u16* __restrict__ qg, const u16* __restrict__ kg,
    const u16* __restrict__ vt, u16* __restrict__ o)
{
  __shared__ u16 Qs[128*64];   // 16KB; per-wave 4KB quarters become Ps after hoist
  __shared__ u16 Ks[64*64];    // 8KB
  __shared__ u16 Vs[64*64];    // 8KB (d-major: row=d, col=kv)

  const int tid = threadIdx.x, lane = tid&63, wave = tid>>6;
  const int cl = lane&15, rg = lane>>4;
  const int bh = blockIdx.x;
  const int q0 = blockIdx.y*128;
  const int b = bh>>4, h = bh&15;
  const size_t qk0 = (size_t)b*SS*EMB + h*64;
  const u16* vtb = vt + (size_t)bh*64*SS;
  const int wbase = wave*1024;

  // stage Q tile (pre-swizzled source)
  #pragma unroll
  for (int p=0;p<4;p++){
    int c = p*256+tid, row = c>>3, j = c&7;
    int d0 = ((j ^ (row&7))<<3);
    stage16(qg + qk0 + (size_t)(q0+row)*EMB + d0, (char*)Qs + p*4096 + wbase);
  }
  __syncthreads();

  // hoist Q fragments (swizzled read)
  s16x8 qf[2][2];
  #pragma unroll
  for (int mi=0;mi<2;mi++)
    #pragma unroll
    for (int kk2=0;kk2<2;kk2++){
      int row = wave*32 + mi*16 + cl;
      qf[mi][kk2] = *(const s16x8*)&Qs[row*64 + (((kk2*4+rg) ^ (row&7))<<3)];
    }

  u16* PsW = Qs + wave*2048;   // this wave's 32x64 swizzled P tile (rows 0..31)

  float mrun[2][4], lrun[2][4];
  f32x4 oacc[2][4];
  #pragma unroll
  for (int i=0;i<2;i++)
    #pragma unroll
    for (int r=0;r<4;r++){ mrun[i][r] = -1e30f; lrun[i][r] = 0.f; }
  #pragma unroll
  for (int i=0;i<2;i++)
    #pragma unroll
    for (int j=0;j<4;j++)
      #pragma unroll
      for (int r=0;r<4;r++) oacc[i][j][r] = 0.f;

  const int rowbase = q0 + wave*32;
  const int nt = (q0 + 128)/64;
  const float SCL = 0.125f * 1.44269504088896340736f;  // 1/sqrt(64) * log2(e)

  for (int t=0;t<nt;t++){
    int kv0 = t*64;
    __syncthreads();
    #pragma unroll
    for (int p=0;p<2;p++){
      int c = p*256+tid, row = c>>3, j = c&7;
      int d0 = ((j ^ (row&7))<<3);
      stage16(kg + qk0 + (size_t)(kv0+row)*EMB + d0, (char*)Ks + p*4096 + wbase);
      stage16(vtb + (size_t)row*SS + kv0 + d0,       (char*)Vs + p*4096 + wbase);
    }
    __syncthreads();

    if (kv0 <= rowbase + 31) {            // wave has at least one unmasked col
      f32x4 sc[2][4];
      #pragma unroll
      for (int i=0;i<2;i++)
        #pragma unroll
        for (int j=0;j<4;j++)
          #pragma unroll
          for (int r=0;r<4;r++) sc[i][j][r] = 0.f;

      #pragma unroll
      for (int kk2=0;kk2<2;kk2++){
        s16x8 kf[4];
        #pragma unroll
        for (int nj=0;nj<4;nj++){
          int row = nj*16+cl;
          kf[nj] = *(const s16x8*)&Ks[row*64 + (((kk2*4+rg) ^ (row&7))<<3)];
        }
        #pragma unroll
        for (int mi=0;mi<2;mi++)
          #pragma unroll
          for (int nj=0;nj<4;nj++)
            sc[mi][nj] = __builtin_amdgcn_mfma_f32_16x16x32_bf16(qf[mi][kk2], kf[nj], sc[mi][nj], 0,0,0);
      }

      const bool full = (kv0 + 63) <= rowbase;   // whole tile unmasked for this wave
      #pragma unroll
      for (int mi=0;mi<2;mi++){
        #pragma unroll
        for (int r=0;r<4;r++){
          int row = rowbase + mi*16 + rg*4 + r;
          float mx = -1e30f;
          #pragma unroll
          for (int nj=0;nj<4;nj++){
            float vv = sc[mi][nj][r]*SCL;
            if (!full){ int col = kv0 + nj*16 + cl; vv = (col<=row) ? vv : -1e30f; }
            sc[mi][nj][r] = vv; mx = fmaxf(mx, vv);
          }
          #pragma unroll
          for (int off=1;off<16;off<<=1) mx = fmaxf(mx, __shfl_xor(mx, off, 64));
          float mn = fmaxf(mrun[mi][r], mx);
          float corr = __builtin_amdgcn_exp2f(mrun[mi][r] - mn);
          mrun[mi][r] = mn;
          float rs = 0.f;
          #pragma unroll
          for (int nj=0;nj<4;nj++){
            float pv = __builtin_amdgcn_exp2f(sc[mi][nj][r] - mn);
            sc[mi][nj][r] = pv; rs += pv;
          }
          #pragma unroll
          for (int off=1;off<16;off<<=1) rs += __shfl_xor(rs, off, 64);
          lrun[mi][r] = lrun[mi][r]*corr + rs;
          #pragma unroll
          for (int nj=0;nj<4;nj++) oacc[mi][nj][r] *= corr;
        }
      }

      // P -> LDS bf16 (packed cvt, swizzled scalar stores)
      #pragma unroll
      for (int mi=0;mi<2;mi++)
        #pragma unroll
        for (int nj=0;nj<4;nj++){
          uint32_t pk01, pk23;
          asm("v_cvt_pk_bf16_f32 %0, %1, %2" : "=v"(pk01) : "v"(sc[mi][nj][0]), "v"(sc[mi][nj][1]));
          asm("v_cvt_pk_bf16_f32 %0, %1, %2" : "=v"(pk23) : "v"(sc[mi][nj][2]), "v"(sc[mi][nj][3]));
          int e = nj*16+cl, ch = e>>3, el = e&7;
          int r0 = mi*16 + rg*4;
          PsW[(r0+0)*64 + ((ch^((r0+0)&7))<<3) + el] = (u16)(pk01 & 0xffffu);
          PsW[(r0+1)*64 + ((ch^((r0+1)&7))<<3) + el] = (u16)(pk01 >> 16);
          PsW[(r0+2)*64 + ((ch^((r0+2)&7))<<3) + el] = (u16)(pk23 & 0xffffu);
          PsW[(r0+3)*64 + ((ch^((r0+3)&7))<<3) + el] = (u16)(pk23 >> 16);
        }

      // PV: O += P @ V  (swizzled reads)
      #pragma unroll
      for (int kk2=0;kk2<2;kk2++){
        s16x8 pf[2], vf[4];
        #pragma unroll
        for (int mi=0;mi<2;mi++){
          int row = mi*16+cl;
          pf[mi] = *(const s16x8*)&PsW[row*64 + (((kk2*4+rg) ^ (row&7))<<3)];
        }
        #pragma unroll
        for (int nj=0;nj<4;nj++){
          int row = nj*16+cl;
          vf[nj] = *(const s16x8*)&Vs[row*64 + (((kk2*4+rg) ^ (row&7))<<3)];
        }
        #pragma unroll
        for (int mi=0;mi<2;mi++)
          #pragma unroll
          for (int nj=0;nj<4;nj++)
            oacc[mi][nj] = __builtin_amdgcn_mfma_f32_16x16x32_bf16(pf[mi], vf[nj], oacc[mi][nj], 0,0,0);
      }
    }
  }

  // epilogue in SCRAMBLED reference layout:
  // o[b][h*128 + (q>>4)][(q&15)*64 + d],  d = nj*16+cl, q = rowbase+mi*16+rg*4+r
  #pragma unroll
  for (int mi=0;mi<2;mi++)
    #pragma unroll
    for (int nj=0;nj<4;nj++)
      #pragma unroll
      for (int r=0;r<4;r++){
        int row = rowbase + mi*16 + rg*4 + r;
        float val = oacc[mi][nj][r] / lrun[mi][r];
        int sp = h*128 + (row>>4);
        int ep = (row&15)*64 + nj*16 + cl;
        o[((size_t)b*SS + sp)*EMB + ep] = f2bf(val);
      }
}

// ---------------- launch ----------------
extern "C" void kernel_launch(void* const* d_in, const int* in_sizes, int n_in,
                              void* d_out, int out_size, void* d_ws, size_t ws_size,
                              hipStream_t stream)
{
  const float* x  = (const float*)d_in[0];
  const float* Wq = (const float*)d_in[1];
  const float* Wk = (const float*)d_in[2];
  const float* Wv = (const float*)d_in[3];
  const float* Wp = (const float*)d_in[4];
  const float* bp = (const float*)d_in[5];
  float* out = (float*)d_out;

  char* ws = (char*)d_ws;
  const size_t XE = (size_t)MR*EMB*2;      // 16MB
  const size_t WE = (size_t)EMB*EMB*2;     // 2MB
  u16* xb  = (u16*)ws; ws += XE;           // x bf16; reused as vt after GEMM1
  u16* wqb = (u16*)ws; ws += WE;
  u16* wkb = (u16*)ws; ws += WE;
  u16* wvb = (u16*)ws; ws += WE;
  u16* wpb = (u16*)ws; ws += WE;
  u16* qb  = (u16*)ws; ws += XE;
  u16* kb  = (u16*)ws; ws += XE;
  u16* vb  = (u16*)ws; ws += XE;           // v bf16; reused as attn-out after k_vt
  float2* tab = (float2*)ws; ws += (size_t)SS*32*sizeof(float2);
  u16* vtb = xb;                           // alias: x dead after GEMM1
  u16* ob  = vb;                           // alias: v dead after k_vt

  k_tables<<<(SS*32+255)/256, 256, 0, stream>>>(tab);
  k_cvt<<<(MR*EMB/4+255)/256, 256, 0, stream>>>(x,  xb,  MR*EMB);
  k_cvt<<<(EMB*EMB/4+255)/256, 256, 0, stream>>>(Wq, wqb, EMB*EMB);
  k_cvt<<<(EMB*EMB/4+255)/256, 256, 0, stream>>>(Wk, wkb, EMB*EMB);
  k_cvt<<<(EMB*EMB/4+255)/256, 256, 0, stream>>>(Wv, wvb, EMB*EMB);
  k_cvt<<<(EMB*EMB/4+255)/256, 256, 0, stream>>>(Wp, wpb, EMB*EMB);

  dim3 g1(MR/128, EMB/128, 3);
  k_gemm<0><<<g1, 256, 0, stream>>>(xb, wqb, wkb, wvb, qb, kb, vb, nullptr, nullptr);

  k_rope<<<(2*(MR*EMB/8))/256, 256, 0, stream>>>(qb, kb, tab);
  k_vt<<<dim3(BB*NHEADS, SS/64), 256, 0, stream>>>(vb, vtb);
  k_attn<<<dim3(BB*NHEADS, SS/128), 256, 0, stream>>>(qb, kb, vtb, ob);

  dim3 g2(MR/128, EMB/128, 1);
  k_gemm<1><<<g2, 256, 0, stream>>>(ob, wpb, nullptr, nullptr, nullptr, nullptr, nullptr, bp, out);
}

// Round 5
// 226.056 us; speedup vs baseline: 1.4810x; 1.2176x over previous
//
#include <hip/hip_runtime.h>
#include <stdint.h>

#define EMB 1024
#define NHEADS 16
#define HDIM 64
#define BB 4
#define SS 2048
#define MR (BB*SS)   // 8192 rows

typedef float f32x4 __attribute__((ext_vector_type(4)));
typedef short s16x8 __attribute__((ext_vector_type(8)));
typedef unsigned short u16;
typedef u16 u16x8 __attribute__((ext_vector_type(8)));

__device__ __forceinline__ float bf2f(u16 h){
  union{uint32_t u;float f;} v; v.u = ((uint32_t)h)<<16; return v.f;
}
__device__ __forceinline__ u16 f2bf(float f){
  union{float f;uint32_t u;} v; v.f=f; uint32_t u=v.u;
  return (u16)((u + 0x7FFFu + ((u>>16)&1u)) >> 16);   // RNE
}

// async global->LDS, 16B per lane. LDS dest = wave-uniform base + lane*16.
__device__ __forceinline__ void stage16(const void* g, void* lds_base){
  __builtin_amdgcn_global_load_lds(
      (__attribute__((address_space(1))) void*)(g),
      (__attribute__((address_space(3))) void*)(lds_base),
      16, 0, 0);
}

// ---------------- rope table: [s][j] cos/sin, j = pair index 0..31 ----------------
__global__ void k_tables(float2* __restrict__ tab){
  int idx = blockIdx.x*256 + threadIdx.x;
  if (idx >= SS*32) return;
  int s = idx >> 5, j = idx & 31;
  double ntk = (double)SS / 1024.0;                        // seq_len / BLOCK_SIZE
  double invf = pow(10000.0, -((double)(2*j))/(64.0*ntk)); // 10000^(-i/(D*ntk))
  double p = (double)s / 1024.0;
  double scal = 1.0 / sqrt(1.0 + p*p);                     // yarn scaling (alpha=1)
  double th = (double)s * invf * scal;
  tab[idx] = make_float2((float)cos(th), (float)sin(th));
}

// ---------------- f32 -> bf16, 4/thread ----------------
__global__ void k_cvt(const float* __restrict__ in, u16* __restrict__ out, int n){
  int i = (blockIdx.x*256 + threadIdx.x)*4;
  if (i >= n) return;
  float4 v = *(const float4*)(in + i);
  union{u16 a[4]; uint64_t q;} pk;
  pk.a[0]=f2bf(v.x); pk.a[1]=f2bf(v.y); pk.a[2]=f2bf(v.z); pk.a[3]=f2bf(v.w);
  *(uint64_t*)(out + i) = pk.q;
}

// ---------------- in-place RoPE on q and k (bf16 [B,S,E]) ----------------
__global__ void k_rope(u16* __restrict__ q, u16* __restrict__ kk,
                       const float2* __restrict__ tab){
  const size_t nper = (size_t)MR*EMB/8;
  size_t t = (size_t)blockIdx.x*256 + threadIdx.x;
  u16* buf = q;
  if (t >= nper){ buf = kk; t -= nper; }
  size_t base = t*8;
  int e = (int)(base & (EMB-1));
  int d = e & 63;
  int s = (int)((base >> 10) & (SS-1));
  const float2* tr = tab + s*32 + (d>>1);
  u16x8 v = *(const u16x8*)(buf + base);
  u16x8 o;
  #pragma unroll
  for (int p=0;p<4;p++){
    float2 cs = tr[p];
    float ev = bf2f(v[2*p]), od = bf2f(v[2*p+1]);
    o[2*p]   = f2bf(ev*cs.x - od*cs.y);
    o[2*p+1] = f2bf(ev*cs.y + od*cs.x);
  }
  *(u16x8*)(buf + base) = o;
}

// ---------------- V transpose: [B,S,E] -> vt[bh][d][s] ----------------
__global__ void k_vt(const u16* __restrict__ v, u16* __restrict__ vt){
  __shared__ u16 tl[64][80];   // pad; 160B row stride keeps 16B alignment
  int bh = blockIdx.x, s0 = blockIdx.y*64;
  int b = bh>>4, h = bh&15;
  int tid = threadIdx.x;
  #pragma unroll
  for (int p=0;p<2;p++){
    int c = p*256+tid, s = c>>3, d0 = (c&7)*8;
    u16x8 x = *(const u16x8*)(v + ((size_t)(b*SS + s0+s))*EMB + h*64 + d0);
    *(u16x8*)&tl[s][d0] = x;
  }
  __syncthreads();
  #pragma unroll
  for (int p=0;p<2;p++){
    int c = p*256+tid, d = c>>3, sc = (c&7)*8;
    u16x8 x;
    #pragma unroll
    for (int i=0;i<8;i++) x[i] = tl[sc+i][d];
    *(u16x8*)(vt + ((size_t)bh*64 + d)*SS + s0 + sc) = x;
  }
}

// ---------------- bt-GEMM (m97 structure): C[m][n] = sum_k A[m][k]*B[n][k] ----------------
// MODE 0: 3 outputs (z selects W/C), bf16 out. MODE 1: f32 out + bias.
template<int MODE>
__global__ __launch_bounds__(256) void k_gemm(
    const u16* __restrict__ A,
    const u16* __restrict__ B0, const u16* __restrict__ B1, const u16* __restrict__ B2,
    u16* __restrict__ C0, u16* __restrict__ C1, u16* __restrict__ C2,
    const float* __restrict__ bias, float* __restrict__ Cf)
{
  constexpr int K = EMB;
  __shared__ u16 As[128][32];
  __shared__ u16 Bs[128][32];
  const int tid = threadIdx.x, lane = tid & 63, wave = tid >> 6;
  const int wr = wave >> 1, wc = wave & 1;
  const int m0 = blockIdx.x*128, n0 = blockIdx.y*128;
  const u16* Bm = (MODE==1) ? B0 : (blockIdx.z==0 ? B0 : (blockIdx.z==1 ? B1 : B2));
  u16* Cb = (blockIdx.z==0 ? C0 : (blockIdx.z==1 ? C1 : C2));

  f32x4 acc[4][4];
  #pragma unroll
  for (int i=0;i<4;i++)
    #pragma unroll
    for (int j=0;j<4;j++)
      #pragma unroll
      for (int r=0;r<4;r++) acc[i][j][r] = 0.f;

  const int cl = lane & 15, kq = (lane>>4)*8, rg = lane>>4;
  char* AsB = (char*)&As[0][0];
  char* BsB = (char*)&Bs[0][0];
  const int wbase = wave*1024;

  for (int k0 = 0; k0 < K; k0 += 32) {
    __syncthreads();
    #pragma unroll
    for (int p=0;p<2;p++){
      int c = p*256 + tid;
      int row = c>>2, sub = c&3;
      stage16(A  + (size_t)(m0+row)*K + k0 + sub*8, AsB + p*4096 + wbase);
      stage16(Bm + (size_t)(n0+row)*K + k0 + sub*8, BsB + p*4096 + wbase);
    }
    __syncthreads();
    s16x8 a[4], b[4];
    #pragma unroll
    for (int i=0;i<4;i++){
      a[i] = *(const s16x8*)&As[wr*64 + i*16 + cl][kq];
      b[i] = *(const s16x8*)&Bs[wc*64 + i*16 + cl][kq];
    }
    #pragma unroll
    for (int i=0;i<4;i++)
      #pragma unroll
      for (int j=0;j<4;j++)
        acc[i][j] = __builtin_amdgcn_mfma_f32_16x16x32_bf16(a[i], b[j], acc[i][j], 0, 0, 0);
  }

  // C layout: col = lane&15, row = (lane>>4)*4 + r  [m89]
  #pragma unroll
  for (int i=0;i<4;i++)
    #pragma unroll
    for (int j=0;j<4;j++){
      int col = n0 + wc*64 + j*16 + cl;
      #pragma unroll
      for (int r=0;r<4;r++){
        int row = m0 + wr*64 + i*16 + rg*4 + r;
        if constexpr (MODE==0){
          Cb[(size_t)row*EMB + col] = f2bf(acc[i][j][r]);
        } else {
          Cf[(size_t)row*EMB + col] = acc[i][j][r] + bias[col];
        }
      }
    }
}

// ---------------- flash attention: 1 block per (bh, 128-row q tile) ----------------
// Swapped QK^T (S^T = mfma(K,Q)): each lane owns q-col cl -> row softmax is
// in-register + 2 shfl_xor. T13 defer-max skips the O-rescale when the tile max
// doesn't exceed the running max by >8 (log2 units; P <= 2^8). P staged to LDS
// as b64 stores (4 consecutive k per lane). All LDS tiles XOR-swizzled (T2).
// Output in the reference's scrambled-reshape layout:
//   ob[b][h*128 + (q>>4)][(q&15)*64 + d]
__global__ __launch_bounds__(256) void k_attn(
    const u16* __restrict__ qg, const u16* __restrict__ kg,
    const u16* __restrict__ vt, u16* __restrict__ o)
{
  __shared__ u16 Qs[128*64];   // 16KB; per-wave 4KB quarters become Ps after hoist
  __shared__ u16 Ks[64*64];    // 8KB
  __shared__ u16 Vs[64*64];    // 8KB (d-major: row=d, col=kv)

  const int tid = threadIdx.x, lane = tid&63, wave = tid>>6;
  const int cl = lane&15, rg = lane>>4;
  const int rg4 = rg*4;
  const int bh = blockIdx.x;
  const int q0 = blockIdx.y*128;
  const int b = bh>>4, h = bh&15;
  const size_t qk0 = (size_t)b*SS*EMB + h*64;
  const u16* vtb = vt + (size_t)bh*64*SS;
  const int wbase = wave*1024;

  // stage Q tile (pre-swizzled source)
  #pragma unroll
  for (int p=0;p<4;p++){
    int c = p*256+tid, row = c>>3, j = c&7;
    int d0 = ((j ^ (row&7))<<3);
    stage16(qg + qk0 + (size_t)(q0+row)*EMB + d0, (char*)Qs + p*4096 + wbase);
  }
  __syncthreads();

  // hoist Q fragments (swizzled read)
  s16x8 qf[2][2];
  #pragma unroll
  for (int mi=0;mi<2;mi++)
    #pragma unroll
    for (int kk2=0;kk2<2;kk2++){
      int row = wave*32 + mi*16 + cl;
      qf[mi][kk2] = *(const s16x8*)&Qs[row*64 + (((kk2*4+rg) ^ (row&7))<<3)];
    }

  u16* PsW = Qs + wave*2048;   // this wave's 32x64 swizzled P tile (rows 0..31)

  float mrun[2], lrun[2];
  f32x4 oacc[2][4];
  #pragma unroll
  for (int i=0;i<2;i++){ mrun[i] = -1e30f; lrun[i] = 0.f; }
  #pragma unroll
  for (int i=0;i<2;i++)
    #pragma unroll
    for (int j=0;j<4;j++)
      #pragma unroll
      for (int r=0;r<4;r++) oacc[i][j][r] = 0.f;

  const int rowbase = q0 + wave*32;
  const int nt = (q0 + 128)/64;
  const float SCL = 0.125f * 1.44269504088896340736f;  // 1/sqrt(64) * log2(e)

  for (int t=0;t<nt;t++){
    int kv0 = t*64;
    __syncthreads();
    #pragma unroll
    for (int p=0;p<2;p++){
      int c = p*256+tid, row = c>>3, j = c&7;
      int d0 = ((j ^ (row&7))<<3);
      stage16(kg + qk0 + (size_t)(kv0+row)*EMB + d0, (char*)Ks + p*4096 + wbase);
      stage16(vtb + (size_t)row*SS + kv0 + d0,       (char*)Vs + p*4096 + wbase);
    }
    __syncthreads();

    if (kv0 <= rowbase + 31) {            // wave has at least one unmasked col
      // S^T = K Q^T: st[nk][mq]: col = q (mq*16+cl), row = k (nk*16+rg*4+r)
      f32x4 st[4][2];
      #pragma unroll
      for (int i=0;i<4;i++)
        #pragma unroll
        for (int j=0;j<2;j++)
          #pragma unroll
          for (int r=0;r<4;r++) st[i][j][r] = 0.f;

      #pragma unroll
      for (int kk2=0;kk2<2;kk2++){
        s16x8 kf[4];
        #pragma unroll
        for (int nk=0;nk<4;nk++){
          int row = nk*16+cl;
          kf[nk] = *(const s16x8*)&Ks[row*64 + (((kk2*4+rg) ^ (row&7))<<3)];
        }
        #pragma unroll
        for (int nk=0;nk<4;nk++)
          #pragma unroll
          for (int mq=0;mq<2;mq++)
            st[nk][mq] = __builtin_amdgcn_mfma_f32_16x16x32_bf16(kf[nk], qf[mq][kk2], st[nk][mq], 0,0,0);
      }

      const bool full = (kv0 + 63) <= rowbase;   // whole tile unmasked for this wave
      float mx[2];
      #pragma unroll
      for (int mq=0;mq<2;mq++){
        int qgr = rowbase + mq*16 + cl;
        float a0 = -1e30f, a1 = -1e30f;
        #pragma unroll
        for (int nk=0;nk<4;nk++){
          #pragma unroll
          for (int r=0;r<4;r++){
            float vv = st[nk][mq][r]*SCL;
            if (!full){ int kgi = kv0 + nk*16 + rg4 + r; vv = (kgi<=qgr) ? vv : -1e30f; }
            st[nk][mq][r] = vv;
            if (r&1) a1 = fmaxf(a1, vv); else a0 = fmaxf(a0, vv);
          }
        }
        float m0 = fmaxf(a0, a1);
        m0 = fmaxf(m0, __shfl_xor(m0, 16, 64));
        m0 = fmaxf(m0, __shfl_xor(m0, 32, 64));
        mx[mq] = m0;
      }

      // T13 defer-max: only rescale when tile max grows past mrun+8
      bool need = (mx[0] > mrun[0] + 8.f) || (mx[1] > mrun[1] + 8.f);
      if (__any(need)) {
        #pragma unroll
        for (int mq=0;mq<2;mq++){
          float mn = fmaxf(mrun[mq], mx[mq]);
          float corr = __builtin_amdgcn_exp2f(mrun[mq] - mn);
          mrun[mq] = mn;
          lrun[mq] *= corr;
          #pragma unroll
          for (int r=0;r<4;r++){
            float cb = __shfl(corr, (lane & 48) | (rg4 + r), 64);
            #pragma unroll
            for (int nj=0;nj<4;nj++) oacc[mq][nj][r] *= cb;
          }
        }
      }

      // P = exp2(S - m), row-sum, and pack to LDS (b64 per (mq,nk))
      #pragma unroll
      for (int mq=0;mq<2;mq++){
        float rs = 0.f;
        #pragma unroll
        for (int nk=0;nk<4;nk++){
          #pragma unroll
          for (int r=0;r<4;r++){
            float pv = __builtin_amdgcn_exp2f(st[nk][mq][r] - mrun[mq]);
            st[nk][mq][r] = pv; rs += pv;
          }
        }
        rs += __shfl_xor(rs, 16, 64);
        rs += __shfl_xor(rs, 32, 64);
        lrun[mq] += rs;

        int q = mq*16 + cl;
        #pragma unroll
        for (int nk=0;nk<4;nk++){
          uint32_t pk01, pk23;
          asm("v_cvt_pk_bf16_f32 %0, %1, %2" : "=v"(pk01) : "v"(st[nk][mq][0]), "v"(st[nk][mq][1]));
          asm("v_cvt_pk_bf16_f32 %0, %1, %2" : "=v"(pk23) : "v"(st[nk][mq][2]), "v"(st[nk][mq][3]));
          int k0e = nk*16 + rg4;          // 4-aligned, 4 consecutive k
          int ch = k0e>>3, el = k0e&7;    // el = 0 or 4
          char* p = (char*)PsW + q*128 + ((ch ^ (q&7))<<4) + el*2;
          *(uint2*)p = make_uint2(pk01, pk23);
        }
      }

      // PV: O += P @ V  (swizzled reads)
      #pragma unroll
      for (int kk2=0;kk2<2;kk2++){
        s16x8 pf[2], vf[4];
        #pragma unroll
        for (int mi=0;mi<2;mi++){
          int row = mi*16+cl;
          pf[mi] = *(const s16x8*)&PsW[row*64 + (((kk2*4+rg) ^ (row&7))<<3)];
        }
        #pragma unroll
        for (int nj=0;nj<4;nj++){
          int row = nj*16+cl;
          vf[nj] = *(const s16x8*)&Vs[row*64 + (((kk2*4+rg) ^ (row&7))<<3)];
        }
        #pragma unroll
        for (int mi=0;mi<2;mi++)
          #pragma unroll
          for (int nj=0;nj<4;nj++)
            oacc[mi][nj] = __builtin_amdgcn_mfma_f32_16x16x32_bf16(pf[mi], vf[nj], oacc[mi][nj], 0,0,0);
      }
    }
  }

  // epilogue in SCRAMBLED reference layout:
  // o[b][h*128 + (q>>4)][(q&15)*64 + d],  d = nj*16+cl, q = rowbase+mi*16+rg4+r
  #pragma unroll
  for (int mi=0;mi<2;mi++)
    #pragma unroll
    for (int r=0;r<4;r++){
      float lb = __shfl(lrun[mi], (lane & 48) | (rg4 + r), 64);
      float linv = 1.f / lb;
      int row = rowbase + mi*16 + rg4 + r;
      int sp = h*128 + (row>>4);
      int epb = (row&15)*64;
      #pragma unroll
      for (int nj=0;nj<4;nj++)
        o[((size_t)b*SS + sp)*EMB + epb + nj*16 + cl] = f2bf(oacc[mi][nj][r]*linv);
    }
}

// ---------------- launch ----------------
extern "C" void kernel_launch(void* const* d_in, const int* in_sizes, int n_in,
                              void* d_out, int out_size, void* d_ws, size_t ws_size,
                              hipStream_t stream)
{
  const float* x  = (const float*)d_in[0];
  const float* Wq = (const float*)d_in[1];
  const float* Wk = (const float*)d_in[2];
  const float* Wv = (const float*)d_in[3];
  const float* Wp = (const float*)d_in[4];
  const float* bp = (const float*)d_in[5];
  float* out = (float*)d_out;

  char* ws = (char*)d_ws;
  const size_t XE = (size_t)MR*EMB*2;      // 16MB
  const size_t WE = (size_t)EMB*EMB*2;     // 2MB
  u16* xb  = (u16*)ws; ws += XE;           // x bf16; reused as vt after GEMM1
  u16* wqb = (u16*)ws; ws += WE;
  u16* wkb = (u16*)ws; ws += WE;
  u16* wvb = (u16*)ws; ws += WE;
  u16* wpb = (u16*)ws; ws += WE;
  u16* qb  = (u16*)ws; ws += XE;
  u16* kb  = (u16*)ws; ws += XE;
  u16* vb  = (u16*)ws; ws += XE;           // v bf16; reused as attn-out after k_vt
  float2* tab = (float2*)ws; ws += (size_t)SS*32*sizeof(float2);
  u16* vtb = xb;                           // alias: x dead after GEMM1
  u16* ob  = vb;                           // alias: v dead after k_vt

  k_tables<<<(SS*32+255)/256, 256, 0, stream>>>(tab);
  k_cvt<<<(MR*EMB/4+255)/256, 256, 0, stream>>>(x,  xb,  MR*EMB);
  k_cvt<<<(EMB*EMB/4+255)/256, 256, 0, stream>>>(Wq, wqb, EMB*EMB);
  k_cvt<<<(EMB*EMB/4+255)/256, 256, 0, stream>>>(Wk, wkb, EMB*EMB);
  k_cvt<<<(EMB*EMB/4+255)/256, 256, 0, stream>>>(Wv, wvb, EMB*EMB);
  k_cvt<<<(EMB*EMB/4+255)/256, 256, 0, stream>>>(Wp, wpb, EMB*EMB);

  dim3 g1(MR/128, EMB/128, 3);
  k_gemm<0><<<g1, 256, 0, stream>>>(xb, wqb, wkb, wvb, qb, kb, vb, nullptr, nullptr);

  k_rope<<<(2*(MR*EMB/8))/256, 256, 0, stream>>>(qb, kb, tab);
  k_vt<<<dim3(BB*NHEADS, SS/64), 256, 0, stream>>>(vb, vtb);
  k_attn<<<dim3(BB*NHEADS, SS/128), 256, 0, stream>>>(qb, kb, vtb, ob);

  dim3 g2(MR/128, EMB/128, 1);
  k_gemm<1><<<g2, 256, 0, stream>>>(ob, wpb, nullptr, nullptr, nullptr, nullptr, nullptr, bp, out);
}

// Round 7
// 211.691 us; speedup vs baseline: 1.5815x; 1.0679x over previous
//
#include <hip/hip_runtime.h>
#include <stdint.h>

#define EMB 1024
#define NHEADS 16
#define HDIM 64
#define BB 4
#define SS 2048
#define MR (BB*SS)   // 8192 rows

typedef float f32x4 __attribute__((ext_vector_type(4)));
typedef short s16x8 __attribute__((ext_vector_type(8)));
typedef unsigned short u16;
typedef u16 u16x8 __attribute__((ext_vector_type(8)));

__device__ __forceinline__ float bf2f(u16 h){
  union{uint32_t u;float f;} v; v.u = ((uint32_t)h)<<16; return v.f;
}
__device__ __forceinline__ u16 f2bf(float f){
  union{float f;uint32_t u;} v; v.f=f; uint32_t u=v.u;
  return (u16)((u + 0x7FFFu + ((u>>16)&1u)) >> 16);   // RNE
}

// async global->LDS, 16B per lane. LDS dest = wave-uniform base + lane*16.
__device__ __forceinline__ void stage16(const void* g, void* lds_base){
  __builtin_amdgcn_global_load_lds(
      (__attribute__((address_space(1))) void*)(g),
      (__attribute__((address_space(3))) void*)(lds_base),
      16, 0, 0);
}

// ---------------- rope table: [s][j] cos/sin, j = pair index 0..31 ----------------
__global__ void k_tables(float2* __restrict__ tab){
  int idx = blockIdx.x*256 + threadIdx.x;
  if (idx >= SS*32) return;
  int s = idx >> 5, j = idx & 31;
  double ntk = (double)SS / 1024.0;                        // seq_len / BLOCK_SIZE
  double invf = pow(10000.0, -((double)(2*j))/(64.0*ntk)); // 10000^(-i/(D*ntk))
  double p = (double)s / 1024.0;
  double scal = 1.0 / sqrt(1.0 + p*p);                     // yarn scaling (alpha=1)
  double th = (double)s * invf * scal;
  tab[idx] = make_float2((float)cos(th), (float)sin(th));
}

// ---------------- f32 -> bf16, 4/thread ----------------
__global__ void k_cvt(const float* __restrict__ in, u16* __restrict__ out, int n){
  int i = (blockIdx.x*256 + threadIdx.x)*4;
  if (i >= n) return;
  float4 v = *(const float4*)(in + i);
  union{u16 a[4]; uint64_t q;} pk;
  pk.a[0]=f2bf(v.x); pk.a[1]=f2bf(v.y); pk.a[2]=f2bf(v.z); pk.a[3]=f2bf(v.w);
  *(uint64_t*)(out + i) = pk.q;
}

// ---------------- in-place RoPE on q and k (bf16 [B,S,E]) ----------------
__global__ void k_rope(u16* __restrict__ q, u16* __restrict__ kk,
                       const float2* __restrict__ tab){
  const size_t nper = (size_t)MR*EMB/8;
  size_t t = (size_t)blockIdx.x*256 + threadIdx.x;
  u16* buf = q;
  if (t >= nper){ buf = kk; t -= nper; }
  size_t base = t*8;
  int e = (int)(base & (EMB-1));
  int d = e & 63;
  int s = (int)((base >> 10) & (SS-1));
  const float2* tr = tab + s*32 + (d>>1);
  u16x8 v = *(const u16x8*)(buf + base);
  u16x8 o;
  #pragma unroll
  for (int p=0;p<4;p++){
    float2 cs = tr[p];
    float ev = bf2f(v[2*p]), od = bf2f(v[2*p+1]);
    o[2*p]   = f2bf(ev*cs.x - od*cs.y);
    o[2*p+1] = f2bf(ev*cs.y + od*cs.x);
  }
  *(u16x8*)(buf + base) = o;
}

// ---------------- V transpose: [B,S,E] -> vt[bh][d][s] ----------------
__global__ void k_vt(const u16* __restrict__ v, u16* __restrict__ vt){
  __shared__ u16 tl[64][80];   // pad; 160B row stride keeps 16B alignment
  int bh = blockIdx.x, s0 = blockIdx.y*64;
  int b = bh>>4, h = bh&15;
  int tid = threadIdx.x;
  #pragma unroll
  for (int p=0;p<2;p++){
    int c = p*256+tid, s = c>>3, d0 = (c&7)*8;
    u16x8 x = *(const u16x8*)(v + ((size_t)(b*SS + s0+s))*EMB + h*64 + d0);
    *(u16x8*)&tl[s][d0] = x;
  }
  __syncthreads();
  #pragma unroll
  for (int p=0;p<2;p++){
    int c = p*256+tid, d = c>>3, sc = (c&7)*8;
    u16x8 x;
    #pragma unroll
    for (int i=0;i<8;i++) x[i] = tl[sc+i][d];
    *(u16x8*)(vt + ((size_t)bh*64 + d)*SS + s0 + sc) = x;
  }
}

// ---------------- bt-GEMM (m97 structure): C[m][n] = sum_k A[m][k]*B[n][k] ----------------
// MODE 0: 3 outputs (z selects W/C), bf16 out. MODE 1: f32 out + bias.
template<int MODE>
__global__ __launch_bounds__(256) void k_gemm(
    const u16* __restrict__ A,
    const u16* __restrict__ B0, const u16* __restrict__ B1, const u16* __restrict__ B2,
    u16* __restrict__ C0, u16* __restrict__ C1, u16* __restrict__ C2,
    const float* __restrict__ bias, float* __restrict__ Cf)
{
  constexpr int K = EMB;
  __shared__ u16 As[128][32];
  __shared__ u16 Bs[128][32];
  const int tid = threadIdx.x, lane = tid & 63, wave = tid >> 6;
  const int wr = wave >> 1, wc = wave & 1;
  const int m0 = blockIdx.x*128, n0 = blockIdx.y*128;
  const u16* Bm = (MODE==1) ? B0 : (blockIdx.z==0 ? B0 : (blockIdx.z==1 ? B1 : B2));
  u16* Cb = (blockIdx.z==0 ? C0 : (blockIdx.z==1 ? C1 : C2));

  f32x4 acc[4][4];
  #pragma unroll
  for (int i=0;i<4;i++)
    #pragma unroll
    for (int j=0;j<4;j++)
      #pragma unroll
      for (int r=0;r<4;r++) acc[i][j][r] = 0.f;

  const int cl = lane & 15, kq = (lane>>4)*8, rg = lane>>4;
  char* AsB = (char*)&As[0][0];
  char* BsB = (char*)&Bs[0][0];
  const int wbase = wave*1024;

  for (int k0 = 0; k0 < K; k0 += 32) {
    __syncthreads();
    #pragma unroll
    for (int p=0;p<2;p++){
      int c = p*256 + tid;
      int row = c>>2, sub = c&3;
      stage16(A  + (size_t)(m0+row)*K + k0 + sub*8, AsB + p*4096 + wbase);
      stage16(Bm + (size_t)(n0+row)*K + k0 + sub*8, BsB + p*4096 + wbase);
    }
    __syncthreads();
    s16x8 a[4], b[4];
    #pragma unroll
    for (int i=0;i<4;i++){
      a[i] = *(const s16x8*)&As[wr*64 + i*16 + cl][kq];
      b[i] = *(const s16x8*)&Bs[wc*64 + i*16 + cl][kq];
    }
    #pragma unroll
    for (int i=0;i<4;i++)
      #pragma unroll
      for (int j=0;j<4;j++)
        acc[i][j] = __builtin_amdgcn_mfma_f32_16x16x32_bf16(a[i], b[j], acc[i][j], 0, 0, 0);
  }

  // C layout: col = lane&15, row = (lane>>4)*4 + r  [m89]
  #pragma unroll
  for (int i=0;i<4;i++)
    #pragma unroll
    for (int j=0;j<4;j++){
      int col = n0 + wc*64 + j*16 + cl;
      #pragma unroll
      for (int r=0;r<4;r++){
        int row = m0 + wr*64 + i*16 + rg*4 + r;
        if constexpr (MODE==0){
          Cb[(size_t)row*EMB + col] = f2bf(acc[i][j][r]);
        } else {
          Cf[(size_t)row*EMB + col] = acc[i][j][r] + bias[col];
        }
      }
    }
}

// ---------------- flash attention: 1 block per (bh, 128-row q tile) ----------------
// Swapped QK^T (S^T = mfma(K,Q)) softmax + T13 defer-max + T2 swizzle (as R5),
// now with double-buffered K/V staging (T3 minimum 2-phase): the async
// global_load_lds for tile t+1 is issued BEFORE computing tile t, so the
// end-of-iteration barrier's vmcnt(0) drain happens after compute has covered
// the load latency. q-tiles launched heavy-first (reversed y) for better
// residency scheduling of the causal-imbalanced grid.
// Output in the reference's scrambled-reshape layout:
//   ob[b][h*128 + (q>>4)][(q&15)*64 + d]
__global__ __launch_bounds__(256) void k_attn(
    const u16* __restrict__ qg, const u16* __restrict__ kg,
    const u16* __restrict__ vt, u16* __restrict__ o)
{
  __shared__ u16 Qs[128*64];     // 16KB; per-wave 4KB quarters become Ps after hoist
  __shared__ u16 Ks[2][64*64];   // 16KB double-buffered
  __shared__ u16 Vs[2][64*64];   // 16KB double-buffered (d-major: row=d, col=kv)

  const int tid = threadIdx.x, lane = tid&63, wave = tid>>6;
  const int cl = lane&15, rg = lane>>4;
  const int rg4 = rg*4;
  const int bh = blockIdx.x;
  const int q0 = (SS/128 - 1 - blockIdx.y)*128;   // heavy blocks first
  const int b = bh>>4, h = bh&15;
  const size_t qk0 = (size_t)b*SS*EMB + h*64;
  const u16* vtb = vt + (size_t)bh*64*SS;
  const int wbase = wave*1024;

  const int rowbase = q0 + wave*32;
  const int nt = (q0 + 128)/64;

  // stage Q tile (pre-swizzled source)
  #pragma unroll
  for (int p=0;p<4;p++){
    int c = p*256+tid, row = c>>3, j = c&7;
    int d0 = ((j ^ (row&7))<<3);
    stage16(qg + qk0 + (size_t)(q0+row)*EMB + d0, (char*)Qs + p*4096 + wbase);
  }
  // stage K/V tile 0 into buffer 0
  #pragma unroll
  for (int p=0;p<2;p++){
    int c = p*256+tid, row = c>>3, j = c&7;
    int d0 = ((j ^ (row&7))<<3);
    stage16(kg + qk0 + (size_t)row*EMB + d0, (char*)Ks[0] + p*4096 + wbase);
    stage16(vtb + (size_t)row*SS + d0,       (char*)Vs[0] + p*4096 + wbase);
  }
  __syncthreads();

  // hoist Q fragments (swizzled read)
  s16x8 qf[2][2];
  #pragma unroll
  for (int mi=0;mi<2;mi++)
    #pragma unroll
    for (int kk2=0;kk2<2;kk2++){
      int row = wave*32 + mi*16 + cl;
      qf[mi][kk2] = *(const s16x8*)&Qs[row*64 + (((kk2*4+rg) ^ (row&7))<<3)];
    }

  u16* PsW = Qs + wave*2048;   // this wave's 32x64 swizzled P tile (rows 0..31)

  float mrun[2], lrun[2];
  f32x4 oacc[2][4];
  #pragma unroll
  for (int i=0;i<2;i++){ mrun[i] = -1e30f; lrun[i] = 0.f; }
  #pragma unroll
  for (int i=0;i<2;i++)
    #pragma unroll
    for (int j=0;j<4;j++)
      #pragma unroll
      for (int r=0;r<4;r++) oacc[i][j][r] = 0.f;

  const float SCL = 0.125f * 1.44269504088896340736f;  // 1/sqrt(64) * log2(e)

  for (int t=0;t<nt;t++){
    const int kv0 = t*64;
    const int cur = t&1;

    // prefetch next tile into the other buffer (async; drained by loop-end barrier)
    if (t+1 < nt){
      int kv1 = kv0 + 64;
      #pragma unroll
      for (int p=0;p<2;p++){
        int c = p*256+tid, row = c>>3, j = c&7;
        int d0 = ((j ^ (row&7))<<3);
        stage16(kg + qk0 + (size_t)(kv1+row)*EMB + d0, (char*)Ks[cur^1] + p*4096 + wbase);
        stage16(vtb + (size_t)row*SS + kv1 + d0,       (char*)Vs[cur^1] + p*4096 + wbase);
      }
    }

    if (kv0 <= rowbase + 31) {            // wave has at least one unmasked col
      // S^T = K Q^T: st[nk][mq]: col = q (mq*16+cl), row = k (nk*16+rg*4+r)
      f32x4 st[4][2];
      #pragma unroll
      for (int i=0;i<4;i++)
        #pragma unroll
        for (int j=0;j<2;j++)
          #pragma unroll
          for (int r=0;r<4;r++) st[i][j][r] = 0.f;

      #pragma unroll
      for (int kk2=0;kk2<2;kk2++){
        s16x8 kf[4];
        #pragma unroll
        for (int nk=0;nk<4;nk++){
          int row = nk*16+cl;
          kf[nk] = *(const s16x8*)&Ks[cur][row*64 + (((kk2*4+rg) ^ (row&7))<<3)];
        }
        #pragma unroll
        for (int nk=0;nk<4;nk++)
          #pragma unroll
          for (int mq=0;mq<2;mq++)
            st[nk][mq] = __builtin_amdgcn_mfma_f32_16x16x32_bf16(kf[nk], qf[mq][kk2], st[nk][mq], 0,0,0);
      }

      const bool full = (kv0 + 63) <= rowbase;   // whole tile unmasked for this wave
      float mx[2];
      #pragma unroll
      for (int mq=0;mq<2;mq++){
        int qgr = rowbase + mq*16 + cl;
        float a0 = -1e30f, a1 = -1e30f;
        #pragma unroll
        for (int nk=0;nk<4;nk++){
          #pragma unroll
          for (int r=0;r<4;r++){
            float vv = st[nk][mq][r]*SCL;
            if (!full){ int kgi = kv0 + nk*16 + rg4 + r; vv = (kgi<=qgr) ? vv : -1e30f; }
            st[nk][mq][r] = vv;
            if (r&1) a1 = fmaxf(a1, vv); else a0 = fmaxf(a0, vv);
          }
        }
        float m0 = fmaxf(a0, a1);
        m0 = fmaxf(m0, __shfl_xor(m0, 16, 64));
        m0 = fmaxf(m0, __shfl_xor(m0, 32, 64));
        mx[mq] = m0;
      }

      // T13 defer-max: only rescale when tile max grows past mrun+8
      bool need = (mx[0] > mrun[0] + 8.f) || (mx[1] > mrun[1] + 8.f);
      if (__any(need)) {
        #pragma unroll
        for (int mq=0;mq<2;mq++){
          float mn = fmaxf(mrun[mq], mx[mq]);
          float corr = __builtin_amdgcn_exp2f(mrun[mq] - mn);
          mrun[mq] = mn;
          lrun[mq] *= corr;
          #pragma unroll
          for (int r=0;r<4;r++){
            float cb = __shfl(corr, (lane & 48) | (rg4 + r), 64);
            #pragma unroll
            for (int nj=0;nj<4;nj++) oacc[mq][nj][r] *= cb;
          }
        }
      }

      // P = exp2(S - m), row-sum, and pack to LDS (b64 per (mq,nk))
      #pragma unroll
      for (int mq=0;mq<2;mq++){
        float rs = 0.f;
        #pragma unroll
        for (int nk=0;nk<4;nk++){
          #pragma unroll
          for (int r=0;r<4;r++){
            float pv = __builtin_amdgcn_exp2f(st[nk][mq][r] - mrun[mq]);
            st[nk][mq][r] = pv; rs += pv;
          }
        }
        rs += __shfl_xor(rs, 16, 64);
        rs += __shfl_xor(rs, 32, 64);
        lrun[mq] += rs;

        int q = mq*16 + cl;
        #pragma unroll
        for (int nk=0;nk<4;nk++){
          uint32_t pk01, pk23;
          asm("v_cvt_pk_bf16_f32 %0, %1, %2" : "=v"(pk01) : "v"(st[nk][mq][0]), "v"(st[nk][mq][1]));
          asm("v_cvt_pk_bf16_f32 %0, %1, %2" : "=v"(pk23) : "v"(st[nk][mq][2]), "v"(st[nk][mq][3]));
          int k0e = nk*16 + rg4;          // 4-aligned, 4 consecutive k
          int ch = k0e>>3, el = k0e&7;    // el = 0 or 4
          char* p = (char*)PsW + q*128 + ((ch ^ (q&7))<<4) + el*2;
          *(uint2*)p = make_uint2(pk01, pk23);
        }
      }

      // PV: O += P @ V  (swizzled reads)
      #pragma unroll
      for (int kk2=0;kk2<2;kk2++){
        s16x8 pf[2], vf[4];
        #pragma unroll
        for (int mi=0;mi<2;mi++){
          int row = mi*16+cl;
          pf[mi] = *(const s16x8*)&PsW[row*64 + (((kk2*4+rg) ^ (row&7))<<3)];
        }
        #pragma unroll
        for (int nj=0;nj<4;nj++){
          int row = nj*16+cl;
          vf[nj] = *(const s16x8*)&Vs[cur][row*64 + (((kk2*4+rg) ^ (row&7))<<3)];
        }
        #pragma unroll
        for (int mi=0;mi<2;mi++)
          #pragma unroll
          for (int nj=0;nj<4;nj++)
            oacc[mi][nj] = __builtin_amdgcn_mfma_f32_16x16x32_bf16(pf[mi], vf[nj], oacc[mi][nj], 0,0,0);
      }
    }

    __syncthreads();   // drains the prefetch (vmcnt 0) + P-region reuse safety
  }

  // epilogue in SCRAMBLED reference layout:
  // o[b][h*128 + (q>>4)][(q&15)*64 + d],  d = nj*16+cl, q = rowbase+mi*16+rg4+r
  #pragma unroll
  for (int mi=0;mi<2;mi++)
    #pragma unroll
    for (int r=0;r<4;r++){
      float lb = __shfl(lrun[mi], (lane & 48) | (rg4 + r), 64);
      float linv = 1.f / lb;
      int row = rowbase + mi*16 + rg4 + r;
      int sp = h*128 + (row>>4);
      int epb = (row&15)*64;
      #pragma unroll
      for (int nj=0;nj<4;nj++)
        o[((size_t)b*SS + sp)*EMB + epb + nj*16 + cl] = f2bf(oacc[mi][nj][r]*linv);
    }
}

// ---------------- launch ----------------
extern "C" void kernel_launch(void* const* d_in, const int* in_sizes, int n_in,
                              void* d_out, int out_size, void* d_ws, size_t ws_size,
                              hipStream_t stream)
{
  const float* x  = (const float*)d_in[0];
  const float* Wq = (const float*)d_in[1];
  const float* Wk = (const float*)d_in[2];
  const float* Wv = (const float*)d_in[3];
  const float* Wp = (const float*)d_in[4];
  const float* bp = (const float*)d_in[5];
  float* out = (float*)d_out;

  char* ws = (char*)d_ws;
  const size_t XE = (size_t)MR*EMB*2;      // 16MB
  const size_t WE = (size_t)EMB*EMB*2;     // 2MB
  u16* xb  = (u16*)ws; ws += XE;           // x bf16; reused as vt after GEMM1
  u16* wqb = (u16*)ws; ws += WE;
  u16* wkb = (u16*)ws; ws += WE;
  u16* wvb = (u16*)ws; ws += WE;
  u16* wpb = (u16*)ws; ws += WE;
  u16* qb  = (u16*)ws; ws += XE;
  u16* kb  = (u16*)ws; ws += XE;
  u16* vb  = (u16*)ws; ws += XE;           // v bf16; reused as attn-out after k_vt
  float2* tab = (float2*)ws; ws += (size_t)SS*32*sizeof(float2);
  u16* vtb = xb;                           // alias: x dead after GEMM1
  u16* ob  = vb;                           // alias: v dead after k_vt

  k_tables<<<(SS*32+255)/256, 256, 0, stream>>>(tab);
  k_cvt<<<(MR*EMB/4+255)/256, 256, 0, stream>>>(x,  xb,  MR*EMB);
  k_cvt<<<(EMB*EMB/4+255)/256, 256, 0, stream>>>(Wq, wqb, EMB*EMB);
  k_cvt<<<(EMB*EMB/4+255)/256, 256, 0, stream>>>(Wk, wkb, EMB*EMB);
  k_cvt<<<(EMB*EMB/4+255)/256, 256, 0, stream>>>(Wv, wvb, EMB*EMB);
  k_cvt<<<(EMB*EMB/4+255)/256, 256, 0, stream>>>(Wp, wpb, EMB*EMB);

  dim3 g1(MR/128, EMB/128, 3);
  k_gemm<0><<<g1, 256, 0, stream>>>(xb, wqb, wkb, wvb, qb, kb, vb, nullptr, nullptr);

  k_rope<<<(2*(MR*EMB/8))/256, 256, 0, stream>>>(qb, kb, tab);
  k_vt<<<dim3(BB*NHEADS, SS/64), 256, 0, stream>>>(vb, vtb);
  k_attn<<<dim3(BB*NHEADS, SS/128), 256, 0, stream>>>(qb, kb, vtb, ob);

  dim3 g2(MR/128, EMB/128, 1);
  k_gemm<1><<<g2, 256, 0, stream>>>(ob, wpb, nullptr, nullptr, nullptr, nullptr, nullptr, bp, out);
}

// Round 8
// 201.207 us; speedup vs baseline: 1.6639x; 1.0521x over previous
//
#include <hip/hip_runtime.h>
#include <stdint.h>

#define EMB 1024
#define NHEADS 16
#define HDIM 64
#define BB 4
#define SS 2048
#define MR (BB*SS)   // 8192 rows

typedef float f32x4 __attribute__((ext_vector_type(4)));
typedef short s16x8 __attribute__((ext_vector_type(8)));
typedef unsigned short u16;
typedef u16 u16x8 __attribute__((ext_vector_type(8)));

__device__ __forceinline__ float bf2f(u16 h){
  union{uint32_t u;float f;} v; v.u = ((uint32_t)h)<<16; return v.f;
}
__device__ __forceinline__ u16 f2bf(float f){
  union{float f;uint32_t u;} v; v.f=f; uint32_t u=v.u;
  return (u16)((u + 0x7FFFu + ((u>>16)&1u)) >> 16);   // RNE
}

// async global->LDS, 16B per lane. LDS dest = wave-uniform base + lane*16.
__device__ __forceinline__ void stage16(const void* g, void* lds_base){
  __builtin_amdgcn_global_load_lds(
      (__attribute__((address_space(1))) void*)(g),
      (__attribute__((address_space(3))) void*)(lds_base),
      16, 0, 0);
}

// ---------------- rope table: [s][j] cos/sin, j = pair index 0..31 ----------------
__global__ void k_tables(float2* __restrict__ tab){
  int idx = blockIdx.x*256 + threadIdx.x;
  if (idx >= SS*32) return;
  int s = idx >> 5, j = idx & 31;
  double ntk = (double)SS / 1024.0;                        // seq_len / BLOCK_SIZE
  double invf = pow(10000.0, -((double)(2*j))/(64.0*ntk)); // 10000^(-i/(D*ntk))
  double p = (double)s / 1024.0;
  double scal = 1.0 / sqrt(1.0 + p*p);                     // yarn scaling (alpha=1)
  double th = (double)s * invf * scal;
  tab[idx] = make_float2((float)cos(th), (float)sin(th));
}

// ---------------- f32 -> bf16, 4/thread ----------------
__global__ void k_cvt(const float* __restrict__ in, u16* __restrict__ out, int n){
  int i = (blockIdx.x*256 + threadIdx.x)*4;
  if (i >= n) return;
  float4 v = *(const float4*)(in + i);
  union{u16 a[4]; uint64_t q;} pk;
  pk.a[0]=f2bf(v.x); pk.a[1]=f2bf(v.y); pk.a[2]=f2bf(v.z); pk.a[3]=f2bf(v.w);
  *(uint64_t*)(out + i) = pk.q;
}

// ---------------- fused QKV GEMM (m97 structure) ----------------
// MODE 0: A[8192][1024] @ Wqkv[3072][1024]^T. Epilogue:
//   cols 0-1023   -> RoPE -> Cq (bf16 [B,S,E])
//   cols 1024-2047-> RoPE -> Ck
//   cols 2048-3071-> transposed write -> VT[bh][d][s]
// MODE 1: f32 out + bias (projection).
template<int MODE>
__global__ __launch_bounds__(256) void k_gemm(
    const u16* __restrict__ A, const u16* __restrict__ B,
    u16* __restrict__ Cq, u16* __restrict__ Ck, u16* __restrict__ VT,
    const float* __restrict__ bias, float* __restrict__ Cf,
    const float2* __restrict__ tab)
{
  constexpr int K = EMB;
  __shared__ u16 As[128][32];
  __shared__ u16 Bs[128][32];
  const int tid = threadIdx.x, lane = tid & 63, wave = tid >> 6;
  const int wr = wave >> 1, wc = wave & 1;
  const int m0 = blockIdx.x*128, n0 = blockIdx.y*128;

  f32x4 acc[4][4];
  #pragma unroll
  for (int i=0;i<4;i++)
    #pragma unroll
    for (int j=0;j<4;j++)
      #pragma unroll
      for (int r=0;r<4;r++) acc[i][j][r] = 0.f;

  const int cl = lane & 15, kq = (lane>>4)*8, rg = lane>>4;
  char* AsB = (char*)&As[0][0];
  char* BsB = (char*)&Bs[0][0];
  const int wbase = wave*1024;

  for (int k0 = 0; k0 < K; k0 += 32) {
    __syncthreads();
    #pragma unroll
    for (int p=0;p<2;p++){
      int c = p*256 + tid;
      int row = c>>2, sub = c&3;
      stage16(A + (size_t)(m0+row)*K + k0 + sub*8, AsB + p*4096 + wbase);
      stage16(B + (size_t)(n0+row)*K + k0 + sub*8, BsB + p*4096 + wbase);
    }
    __syncthreads();
    s16x8 a[4], b[4];
    #pragma unroll
    for (int i=0;i<4;i++){
      a[i] = *(const s16x8*)&As[wr*64 + i*16 + cl][kq];
      b[i] = *(const s16x8*)&Bs[wc*64 + i*16 + cl][kq];
    }
    #pragma unroll
    for (int i=0;i<4;i++)
      #pragma unroll
      for (int j=0;j<4;j++)
        acc[i][j] = __builtin_amdgcn_mfma_f32_16x16x32_bf16(a[i], b[j], acc[i][j], 0, 0, 0);
  }

  // C layout: col = lane&15, row = (lane>>4)*4 + r  [m89]
  if constexpr (MODE==1){
    #pragma unroll
    for (int i=0;i<4;i++)
      #pragma unroll
      for (int j=0;j<4;j++){
        int col = n0 + wc*64 + j*16 + cl;
        #pragma unroll
        for (int r=0;r<4;r++){
          int row = m0 + wr*64 + i*16 + rg*4 + r;
          Cf[(size_t)row*EMB + col] = acc[i][j][r] + bias[col];
        }
      }
  } else {
    const int colbase = n0 + wc*64;          // wave-uniform; region uniform per (wave,j)
    #pragma unroll
    for (int i=0;i<4;i++)
      #pragma unroll
      for (int j=0;j<4;j++){
        int col = colbase + j*16 + cl;
        if (col < 2048) {
          // RoPE: pair (even,odd) lives in lanes (cl even, cl odd)
          u16* dst = (col < 1024) ? Cq : Ck;
          int cc = col & 1023;
          int dp = (col & 63) >> 1;          // pair index within head
          #pragma unroll
          for (int r=0;r<4;r++){
            int row = m0 + wr*64 + i*16 + rg*4 + r;
            int s = row & (SS-1);
            float own = acc[i][j][r];
            float par = __shfl_xor(own, 1, 64);
            float2 cs = tab[s*32 + dp];
            float outv = (cl & 1) ? (par*cs.y + own*cs.x)   // odd col: ev*sin + od*cos
                                  : (own*cs.x - par*cs.y);  // even col: ev*cos - od*sin
            dst[(size_t)row*EMB + cc] = f2bf(outv);
          }
        } else {
          // V transposed: vt[bh][d][s], 4 consecutive s per lane -> one b64 store
          int dfull = col - 2048;
          int h = dfull >> 6, d = dfull & 63;
          int row0 = m0 + wr*64 + i*16 + rg*4;
          int bb = row0 >> 11, s0 = row0 & (SS-1);
          union{u16 a4[4]; uint64_t q;} pk;
          #pragma unroll
          for (int r=0;r<4;r++) pk.a4[r] = f2bf(acc[i][j][r]);
          *(uint64_t*)(VT + ((size_t)(bb*NHEADS + h)*64 + d)*SS + s0) = pk.q;
        }
      }
  }
}

// ---------------- flash attention: 1 block per (bh, 128-row q tile) ----------------
// Swapped QK^T (S^T = mfma(K,Q)) softmax, T13 defer-max, T2 swizzle, double-buffered
// K/V prefetch. Full/diagonal tiles take separate wave-uniform paths (masking VALU
// only on diagonal). Row-sum kept as per-lane partial; reduced once in epilogue.
// Output in the reference's scrambled-reshape layout:
//   ob[b][h*128 + (q>>4)][(q&15)*64 + d]
__global__ __launch_bounds__(256) void k_attn(
    const u16* __restrict__ qg, const u16* __restrict__ kg,
    const u16* __restrict__ vt, u16* __restrict__ o)
{
  __shared__ u16 Qs[128*64];     // 16KB; per-wave 4KB quarters become Ps after hoist
  __shared__ u16 Ks[2][64*64];   // 16KB double-buffered
  __shared__ u16 Vs[2][64*64];   // 16KB double-buffered (d-major: row=d, col=kv)

  const int tid = threadIdx.x, lane = tid&63, wave = tid>>6;
  const int cl = lane&15, rg = lane>>4;
  const int rg4 = rg*4;
  const int bh = blockIdx.x;
  const int q0 = (SS/128 - 1 - blockIdx.y)*128;   // heavy blocks first
  const int b = bh>>4, h = bh&15;
  const size_t qk0 = (size_t)b*SS*EMB + h*64;
  const u16* vtb = vt + (size_t)bh*64*SS;
  const int wbase = wave*1024;

  const int rowbase = q0 + wave*32;
  const int nt = (q0 + 128)/64;

  // stage Q tile (pre-swizzled source)
  #pragma unroll
  for (int p=0;p<4;p++){
    int c = p*256+tid, row = c>>3, j = c&7;
    int d0 = ((j ^ (row&7))<<3);
    stage16(qg + qk0 + (size_t)(q0+row)*EMB + d0, (char*)Qs + p*4096 + wbase);
  }
  // stage K/V tile 0 into buffer 0
  #pragma unroll
  for (int p=0;p<2;p++){
    int c = p*256+tid, row = c>>3, j = c&7;
    int d0 = ((j ^ (row&7))<<3);
    stage16(kg + qk0 + (size_t)row*EMB + d0, (char*)Ks[0] + p*4096 + wbase);
    stage16(vtb + (size_t)row*SS + d0,       (char*)Vs[0] + p*4096 + wbase);
  }
  __syncthreads();

  // hoist Q fragments (swizzled read)
  s16x8 qf[2][2];
  #pragma unroll
  for (int mi=0;mi<2;mi++)
    #pragma unroll
    for (int kk2=0;kk2<2;kk2++){
      int row = wave*32 + mi*16 + cl;
      qf[mi][kk2] = *(const s16x8*)&Qs[row*64 + (((kk2*4+rg) ^ (row&7))<<3)];
    }

  u16* PsW = Qs + wave*2048;   // this wave's 32x64 swizzled P tile (rows 0..31)

  float mrun[2], lrun[2];
  f32x4 oacc[2][4];
  #pragma unroll
  for (int i=0;i<2;i++){ mrun[i] = -1e30f; lrun[i] = 0.f; }
  #pragma unroll
  for (int i=0;i<2;i++)
    #pragma unroll
    for (int j=0;j<4;j++)
      #pragma unroll
      for (int r=0;r<4;r++) oacc[i][j][r] = 0.f;

  const float SCL = 0.125f * 1.44269504088896340736f;  // 1/sqrt(64) * log2(e)

  for (int t=0;t<nt;t++){
    const int kv0 = t*64;
    const int cur = t&1;

    // prefetch next tile into the other buffer (async; drained by loop-end barrier)
    if (t+1 < nt){
      int kv1 = kv0 + 64;
      #pragma unroll
      for (int p=0;p<2;p++){
        int c = p*256+tid, row = c>>3, j = c&7;
        int d0 = ((j ^ (row&7))<<3);
        stage16(kg + qk0 + (size_t)(kv1+row)*EMB + d0, (char*)Ks[cur^1] + p*4096 + wbase);
        stage16(vtb + (size_t)row*SS + kv1 + d0,       (char*)Vs[cur^1] + p*4096 + wbase);
      }
    }

    if (kv0 <= rowbase + 31) {            // wave has at least one unmasked col
      // S^T = K Q^T: st[nk][mq]: col = q (mq*16+cl), row = k (nk*16+rg*4+r)
      f32x4 st[4][2];
      #pragma unroll
      for (int i=0;i<4;i++)
        #pragma unroll
        for (int j=0;j<2;j++)
          #pragma unroll
          for (int r=0;r<4;r++) st[i][j][r] = 0.f;

      #pragma unroll
      for (int kk2=0;kk2<2;kk2++){
        s16x8 kf[4];
        #pragma unroll
        for (int nk=0;nk<4;nk++){
          int row = nk*16+cl;
          kf[nk] = *(const s16x8*)&Ks[cur][row*64 + (((kk2*4+rg) ^ (row&7))<<3)];
        }
        #pragma unroll
        for (int nk=0;nk<4;nk++)
          #pragma unroll
          for (int mq=0;mq<2;mq++)
            st[nk][mq] = __builtin_amdgcn_mfma_f32_16x16x32_bf16(kf[nk], qf[mq][kk2], st[nk][mq], 0,0,0);
      }

      const bool full = (kv0 + 63) <= rowbase;   // whole tile unmasked (wave-uniform)
      float mx[2];
      if (full) {
        #pragma unroll
        for (int mq=0;mq<2;mq++){
          float a0 = -1e30f, a1 = -1e30f;
          #pragma unroll
          for (int nk=0;nk<4;nk++){
            #pragma unroll
            for (int r=0;r<4;r++){
              float vv = st[nk][mq][r]*SCL;
              st[nk][mq][r] = vv;
              if (r&1) a1 = fmaxf(a1, vv); else a0 = fmaxf(a0, vv);
            }
          }
          float m0 = fmaxf(a0, a1);
          m0 = fmaxf(m0, __shfl_xor(m0, 16, 64));
          m0 = fmaxf(m0, __shfl_xor(m0, 32, 64));
          mx[mq] = m0;
        }
      } else {
        #pragma unroll
        for (int mq=0;mq<2;mq++){
          int qgr = rowbase + mq*16 + cl;
          float a0 = -1e30f, a1 = -1e30f;
          #pragma unroll
          for (int nk=0;nk<4;nk++){
            #pragma unroll
            for (int r=0;r<4;r++){
              float vv = st[nk][mq][r]*SCL;
              int kgi = kv0 + nk*16 + rg4 + r;
              vv = (kgi<=qgr) ? vv : -1e30f;
              st[nk][mq][r] = vv;
              if (r&1) a1 = fmaxf(a1, vv); else a0 = fmaxf(a0, vv);
            }
          }
          float m0 = fmaxf(a0, a1);
          m0 = fmaxf(m0, __shfl_xor(m0, 16, 64));
          m0 = fmaxf(m0, __shfl_xor(m0, 32, 64));
          mx[mq] = m0;
        }
      }

      // T13 defer-max: only rescale when tile max grows past mrun+8
      bool need = (mx[0] > mrun[0] + 8.f) || (mx[1] > mrun[1] + 8.f);
      if (__any(need)) {
        #pragma unroll
        for (int mq=0;mq<2;mq++){
          float mn = fmaxf(mrun[mq], mx[mq]);
          float corr = __builtin_amdgcn_exp2f(mrun[mq] - mn);
          mrun[mq] = mn;
          lrun[mq] *= corr;
          #pragma unroll
          for (int r=0;r<4;r++){
            float cb = __shfl(corr, (lane & 48) | (rg4 + r), 64);
            #pragma unroll
            for (int nj=0;nj<4;nj++) oacc[mq][nj][r] *= cb;
          }
        }
      }

      // P = exp2(S - m); accumulate PER-LANE partial row-sum (reduced in epilogue);
      // pack to LDS (b64 per (mq,nk))
      #pragma unroll
      for (int mq=0;mq<2;mq++){
        float rs = 0.f;
        #pragma unroll
        for (int nk=0;nk<4;nk++){
          #pragma unroll
          for (int r=0;r<4;r++){
            float pv = __builtin_amdgcn_exp2f(st[nk][mq][r] - mrun[mq]);
            st[nk][mq][r] = pv; rs += pv;
          }
        }
        lrun[mq] += rs;

        int q = mq*16 + cl;
        #pragma unroll
        for (int nk=0;nk<4;nk++){
          uint32_t pk01, pk23;
          asm("v_cvt_pk_bf16_f32 %0, %1, %2" : "=v"(pk01) : "v"(st[nk][mq][0]), "v"(st[nk][mq][1]));
          asm("v_cvt_pk_bf16_f32 %0, %1, %2" : "=v"(pk23) : "v"(st[nk][mq][2]), "v"(st[nk][mq][3]));
          int k0e = nk*16 + rg4;          // 4-aligned, 4 consecutive k
          int ch = k0e>>3, el = k0e&7;    // el = 0 or 4
          char* p = (char*)PsW + q*128 + ((ch ^ (q&7))<<4) + el*2;
          *(uint2*)p = make_uint2(pk01, pk23);
        }
      }

      // PV: O += P @ V  (swizzled reads)
      #pragma unroll
      for (int kk2=0;kk2<2;kk2++){
        s16x8 pf[2], vf[4];
        #pragma unroll
        for (int mi=0;mi<2;mi++){
          int row = mi*16+cl;
          pf[mi] = *(const s16x8*)&PsW[row*64 + (((kk2*4+rg) ^ (row&7))<<3)];
        }
        #pragma unroll
        for (int nj=0;nj<4;nj++){
          int row = nj*16+cl;
          vf[nj] = *(const s16x8*)&Vs[cur][row*64 + (((kk2*4+rg) ^ (row&7))<<3)];
        }
        #pragma unroll
        for (int mi=0;mi<2;mi++)
          #pragma unroll
          for (int nj=0;nj<4;nj++)
            oacc[mi][nj] = __builtin_amdgcn_mfma_f32_16x16x32_bf16(pf[mi], vf[nj], oacc[mi][nj], 0,0,0);
      }
    }

    __syncthreads();   // drains the prefetch (vmcnt 0) + P-region reuse safety
  }

  // epilogue: reduce l across rg groups, then redistribute to C-layout rows.
  // SCRAMBLED reference layout: o[b][h*128 + (q>>4)][(q&15)*64 + d]
  #pragma unroll
  for (int mi=0;mi<2;mi++){
    float lsum = lrun[mi];
    lsum += __shfl_xor(lsum, 16, 64);
    lsum += __shfl_xor(lsum, 32, 64);
    #pragma unroll
    for (int r=0;r<4;r++){
      float lb = __shfl(lsum, (lane & 48) | (rg4 + r), 64);
      float linv = 1.f / lb;
      int row = rowbase + mi*16 + rg4 + r;
      int sp = h*128 + (row>>4);
      int epb = (row&15)*64;
      #pragma unroll
      for (int nj=0;nj<4;nj++)
        o[((size_t)b*SS + sp)*EMB + epb + nj*16 + cl] = f2bf(oacc[mi][nj][r]*linv);
    }
  }
}

// ---------------- launch ----------------
extern "C" void kernel_launch(void* const* d_in, const int* in_sizes, int n_in,
                              void* d_out, int out_size, void* d_ws, size_t ws_size,
                              hipStream_t stream)
{
  const float* x  = (const float*)d_in[0];
  const float* Wq = (const float*)d_in[1];
  const float* Wk = (const float*)d_in[2];
  const float* Wv = (const float*)d_in[3];
  const float* Wp = (const float*)d_in[4];
  const float* bp = (const float*)d_in[5];
  float* out = (float*)d_out;

  char* ws = (char*)d_ws;
  const size_t XE = (size_t)MR*EMB*2;      // 16MB
  const size_t WE = (size_t)EMB*EMB*2;     // 2MB
  u16* xb  = (u16*)ws; ws += XE;           // x bf16; reused as attn-out after GEMM0
  u16* wqb = (u16*)ws; ws += WE;           // wq/wk/wv CONTIGUOUS -> one [3072][1024] B
  u16* wkb = (u16*)ws; ws += WE;
  u16* wvb = (u16*)ws; ws += WE;
  u16* wpb = (u16*)ws; ws += WE;
  u16* qb  = (u16*)ws; ws += XE;
  u16* kb  = (u16*)ws; ws += XE;
  u16* vtb = (u16*)ws; ws += XE;           // V transposed [bh][d][s], written by GEMM0
  float2* tab = (float2*)ws; ws += (size_t)SS*32*sizeof(float2);
  u16* ob  = xb;                           // alias: x dead after GEMM0

  k_tables<<<(SS*32+255)/256, 256, 0, stream>>>(tab);
  k_cvt<<<(MR*EMB/4+255)/256, 256, 0, stream>>>(x,  xb,  MR*EMB);
  k_cvt<<<(EMB*EMB/4+255)/256, 256, 0, stream>>>(Wq, wqb, EMB*EMB);
  k_cvt<<<(EMB*EMB/4+255)/256, 256, 0, stream>>>(Wk, wkb, EMB*EMB);
  k_cvt<<<(EMB*EMB/4+255)/256, 256, 0, stream>>>(Wv, wvb, EMB*EMB);
  k_cvt<<<(EMB*EMB/4+255)/256, 256, 0, stream>>>(Wp, wpb, EMB*EMB);

  dim3 g1(MR/128, 3*EMB/128);
  k_gemm<0><<<g1, 256, 0, stream>>>(xb, wqb, qb, kb, vtb, nullptr, nullptr, tab);

  k_attn<<<dim3(BB*NHEADS, SS/128), 256, 0, stream>>>(qb, kb, vtb, ob);

  dim3 g2(MR/128, EMB/128);
  k_gemm<1><<<g2, 256, 0, stream>>>(ob, wpb, nullptr, nullptr, nullptr, bp, out, nullptr);
}

// Round 9
// 185.147 us; speedup vs baseline: 1.8083x; 1.0867x over previous
//
#include <hip/hip_runtime.h>
#include <stdint.h>

#define EMB 1024
#define NHEADS 16
#define HDIM 64
#define BB 4
#define SS 2048
#define MR (BB*SS)   // 8192 rows

typedef float f32x4 __attribute__((ext_vector_type(4)));
typedef short s16x8 __attribute__((ext_vector_type(8)));
typedef unsigned short u16;
typedef u16 u16x8 __attribute__((ext_vector_type(8)));

__device__ __forceinline__ float bf2f(u16 h){
  union{uint32_t u;float f;} v; v.u = ((uint32_t)h)<<16; return v.f;
}
__device__ __forceinline__ u16 f2bf(float f){
  union{float f;uint32_t u;} v; v.f=f; uint32_t u=v.u;
  return (u16)((u + 0x7FFFu + ((u>>16)&1u)) >> 16);   // RNE
}

// async global->LDS, 16B per lane. LDS dest = wave-uniform base + lane*16.
__device__ __forceinline__ void stage16(const void* g, void* lds_base){
  __builtin_amdgcn_global_load_lds(
      (__attribute__((address_space(1))) void*)(g),
      (__attribute__((address_space(3))) void*)(lds_base),
      16, 0, 0);
}

// ---------------- fused prep: x/W cvt to bf16 + rope table, ONE launch ----------------
// regions: [0, 2M)        -> x cvt, 4 elems/thread
//          [2M, 3M)       -> Wq|Wk|Wv|Wp cvt (contiguous dst), 4 elems/thread
//          [3M, 3M+64K)   -> rope table
__global__ void k_prep(const float* __restrict__ x,
                       const float* __restrict__ Wq, const float* __restrict__ Wk,
                       const float* __restrict__ Wv, const float* __restrict__ Wp,
                       u16* __restrict__ xb, u16* __restrict__ wb,
                       float2* __restrict__ tab){
  unsigned g = blockIdx.x*256 + threadIdx.x;
  if (g < 2097152u){
    unsigned i = g*4;
    float4 v = *(const float4*)(x + i);
    union{u16 a[4]; uint64_t q;} pk;
    pk.a[0]=f2bf(v.x); pk.a[1]=f2bf(v.y); pk.a[2]=f2bf(v.z); pk.a[3]=f2bf(v.w);
    *(uint64_t*)(xb + i) = pk.q;
  } else if (g < 3145728u){
    unsigned e = (g - 2097152u)*4;
    unsigned w = e >> 20;                       // block-uniform (1M%1024==0)
    unsigned off = e & 1048575u;
    const float* s = (w==0)?Wq:(w==1)?Wk:(w==2)?Wv:Wp;
    float4 v = *(const float4*)(s + off);
    union{u16 a[4]; uint64_t q;} pk;
    pk.a[0]=f2bf(v.x); pk.a[1]=f2bf(v.y); pk.a[2]=f2bf(v.z); pk.a[3]=f2bf(v.w);
    *(uint64_t*)(wb + e) = pk.q;
  } else {
    unsigned idx = g - 3145728u;                // 0..65535
    int s = idx >> 5, j = idx & 31;
    double ntk = (double)SS / 1024.0;
    double invf = pow(10000.0, -((double)(2*j))/(64.0*ntk));
    double p = (double)s / 1024.0;
    double scal = 1.0 / sqrt(1.0 + p*p);
    double th = (double)s * invf * scal;
    tab[idx] = make_float2((float)cos(th), (float)sin(th));
  }
}

// ---------------- fused QKV GEMM (m97 structure + dbuf prefetch) ----------------
// MODE 0: A[8192][1024] @ Wqkv[3072][1024]^T. Epilogue:
//   cols 0-1023   -> RoPE -> Cq (bf16 [B,S,E])
//   cols 1024-2047-> RoPE -> Ck
//   cols 2048-3071-> transposed write -> VT[bh][d][s]
// MODE 1: f32 out + bias (projection).
// K-loop: double-buffered LDS; prefetch K-tile k+1 issued BEFORE compute on k;
// single barrier per K-step (drain lands after compute covers the latency).
template<int MODE>
__global__ __launch_bounds__(256) void k_gemm(
    const u16* __restrict__ A, const u16* __restrict__ B,
    u16* __restrict__ Cq, u16* __restrict__ Ck, u16* __restrict__ VT,
    const float* __restrict__ bias, float* __restrict__ Cf,
    const float2* __restrict__ tab)
{
  constexpr int K = EMB;
  __shared__ u16 As[2][128][32];
  __shared__ u16 Bs[2][128][32];
  const int tid = threadIdx.x, lane = tid & 63, wave = tid >> 6;
  const int wr = wave >> 1, wc = wave & 1;
  const int m0 = blockIdx.x*128, n0 = blockIdx.y*128;

  f32x4 acc[4][4];
  #pragma unroll
  for (int i=0;i<4;i++)
    #pragma unroll
    for (int j=0;j<4;j++)
      #pragma unroll
      for (int r=0;r<4;r++) acc[i][j][r] = 0.f;

  const int cl = lane & 15, kq = (lane>>4)*8, rg = lane>>4;
  char* AsB = (char*)&As[0][0][0];
  char* BsB = (char*)&Bs[0][0][0];
  const int wbase = wave*1024;
  const int row_s = (tid>>2), sub8 = (tid&3)*8;       // staging row/sub for pass p=0 base
  // per-pass staging addressing (p in 0..1): row = (p*256+tid)>>2, sub = (p*256+tid)&3

  // prologue: stage K-tile 0 into buffer 0
  #pragma unroll
  for (int p=0;p<2;p++){
    int c = p*256 + tid, row = c>>2, sub = c&3;
    stage16(A + (size_t)(m0+row)*K + sub*8, AsB + p*4096 + wbase);
    stage16(B + (size_t)(n0+row)*K + sub*8, BsB + p*4096 + wbase);
  }
  __syncthreads();

  for (int k0 = 0; k0 < K; k0 += 32) {
    const int cur = (k0>>5)&1;
    // prefetch next K-tile into other buffer
    if (k0 + 32 < K){
      #pragma unroll
      for (int p=0;p<2;p++){
        int c = p*256 + tid, row = c>>2, sub = c&3;
        stage16(A + (size_t)(m0+row)*K + k0+32 + sub*8, AsB + (cur^1)*8192 + p*4096 + wbase);
        stage16(B + (size_t)(n0+row)*K + k0+32 + sub*8, BsB + (cur^1)*8192 + p*4096 + wbase);
      }
    }
    s16x8 a[4], b[4];
    #pragma unroll
    for (int i=0;i<4;i++){
      a[i] = *(const s16x8*)&As[cur][wr*64 + i*16 + cl][kq];
      b[i] = *(const s16x8*)&Bs[cur][wc*64 + i*16 + cl][kq];
    }
    #pragma unroll
    for (int i=0;i<4;i++)
      #pragma unroll
      for (int j=0;j<4;j++)
        acc[i][j] = __builtin_amdgcn_mfma_f32_16x16x32_bf16(a[i], b[j], acc[i][j], 0, 0, 0);
    __syncthreads();   // next tile staged + all reads of cur done
  }

  // C layout: col = lane&15, row = (lane>>4)*4 + r  [m89]
  if constexpr (MODE==1){
    #pragma unroll
    for (int i=0;i<4;i++)
      #pragma unroll
      for (int j=0;j<4;j++){
        int col = n0 + wc*64 + j*16 + cl;
        #pragma unroll
        for (int r=0;r<4;r++){
          int row = m0 + wr*64 + i*16 + rg*4 + r;
          Cf[(size_t)row*EMB + col] = acc[i][j][r] + bias[col];
        }
      }
  } else {
    const int colbase = n0 + wc*64;          // wave-uniform; region uniform per (wave,j)
    #pragma unroll
    for (int i=0;i<4;i++)
      #pragma unroll
      for (int j=0;j<4;j++){
        int col = colbase + j*16 + cl;
        if (col < 2048) {
          // RoPE: pair (even,odd) lives in lanes (cl even, cl odd)
          u16* dst = (col < 1024) ? Cq : Ck;
          int cc = col & 1023;
          int dp = (col & 63) >> 1;          // pair index within head
          #pragma unroll
          for (int r=0;r<4;r++){
            int row = m0 + wr*64 + i*16 + rg*4 + r;
            int s = row & (SS-1);
            float own = acc[i][j][r];
            float par = __shfl_xor(own, 1, 64);
            float2 cs = tab[s*32 + dp];
            float outv = (cl & 1) ? (par*cs.y + own*cs.x)   // odd col: ev*sin + od*cos
                                  : (own*cs.x - par*cs.y);  // even col: ev*cos - od*sin
            dst[(size_t)row*EMB + cc] = f2bf(outv);
          }
        } else {
          // V transposed: vt[bh][d][s], 4 consecutive s per lane -> one b64 store
          int dfull = col - 2048;
          int h = dfull >> 6, d = dfull & 63;
          int row0 = m0 + wr*64 + i*16 + rg*4;
          int bb = row0 >> 11, s0 = row0 & (SS-1);
          union{u16 a4[4]; uint64_t q;} pk;
          #pragma unroll
          for (int r=0;r<4;r++) pk.a4[r] = f2bf(acc[i][j][r]);
          *(uint64_t*)(VT + ((size_t)(bb*NHEADS + h)*64 + d)*SS + s0) = pk.q;
        }
      }
  }
}

// ---------------- flash attention: 1 block per (bh, 128-row q tile) ----------------
// Swapped QK^T (S^T = mfma(K,Q)) softmax, T13 defer-max, T2 swizzle, double-buffered
// K/V prefetch. Full/diagonal tiles take separate wave-uniform paths. Row-sum kept
// as per-lane partial; reduced once in epilogue.
// Output in the reference's scrambled-reshape layout:
//   ob[b][h*128 + (q>>4)][(q&15)*64 + d]
__global__ __launch_bounds__(256) void k_attn(
    const u16* __restrict__ qg, const u16* __restrict__ kg,
    const u16* __restrict__ vt, u16* __restrict__ o)
{
  __shared__ u16 Qs[128*64];     // 16KB; per-wave 4KB quarters become Ps after hoist
  __shared__ u16 Ks[2][64*64];   // 16KB double-buffered
  __shared__ u16 Vs[2][64*64];   // 16KB double-buffered (d-major: row=d, col=kv)

  const int tid = threadIdx.x, lane = tid&63, wave = tid>>6;
  const int cl = lane&15, rg = lane>>4;
  const int rg4 = rg*4;
  const int bh = blockIdx.x;
  const int q0 = (SS/128 - 1 - blockIdx.y)*128;   // heavy blocks first
  const int b = bh>>4, h = bh&15;
  const size_t qk0 = (size_t)b*SS*EMB + h*64;
  const u16* vtb = vt + (size_t)bh*64*SS;
  const int wbase = wave*1024;

  const int rowbase = q0 + wave*32;
  const int nt = (q0 + 128)/64;

  // stage Q tile (pre-swizzled source)
  #pragma unroll
  for (int p=0;p<4;p++){
    int c = p*256+tid, row = c>>3, j = c&7;
    int d0 = ((j ^ (row&7))<<3);
    stage16(qg + qk0 + (size_t)(q0+row)*EMB + d0, (char*)Qs + p*4096 + wbase);
  }
  // stage K/V tile 0 into buffer 0
  #pragma unroll
  for (int p=0;p<2;p++){
    int c = p*256+tid, row = c>>3, j = c&7;
    int d0 = ((j ^ (row&7))<<3);
    stage16(kg + qk0 + (size_t)row*EMB + d0, (char*)Ks[0] + p*4096 + wbase);
    stage16(vtb + (size_t)row*SS + d0,       (char*)Vs[0] + p*4096 + wbase);
  }
  __syncthreads();

  // hoist Q fragments (swizzled read)
  s16x8 qf[2][2];
  #pragma unroll
  for (int mi=0;mi<2;mi++)
    #pragma unroll
    for (int kk2=0;kk2<2;kk2++){
      int row = wave*32 + mi*16 + cl;
      qf[mi][kk2] = *(const s16x8*)&Qs[row*64 + (((kk2*4+rg) ^ (row&7))<<3)];
    }

  u16* PsW = Qs + wave*2048;   // this wave's 32x64 swizzled P tile (rows 0..31)

  float mrun[2], lrun[2];
  f32x4 oacc[2][4];
  #pragma unroll
  for (int i=0;i<2;i++){ mrun[i] = -1e30f; lrun[i] = 0.f; }
  #pragma unroll
  for (int i=0;i<2;i++)
    #pragma unroll
    for (int j=0;j<4;j++)
      #pragma unroll
      for (int r=0;r<4;r++) oacc[i][j][r] = 0.f;

  const float SCL = 0.125f * 1.44269504088896340736f;  // 1/sqrt(64) * log2(e)

  for (int t=0;t<nt;t++){
    const int kv0 = t*64;
    const int cur = t&1;

    // prefetch next tile into the other buffer (async; drained by loop-end barrier)
    if (t+1 < nt){
      int kv1 = kv0 + 64;
      #pragma unroll
      for (int p=0;p<2;p++){
        int c = p*256+tid, row = c>>3, j = c&7;
        int d0 = ((j ^ (row&7))<<3);
        stage16(kg + qk0 + (size_t)(kv1+row)*EMB + d0, (char*)Ks[cur^1] + p*4096 + wbase);
        stage16(vtb + (size_t)row*SS + kv1 + d0,       (char*)Vs[cur^1] + p*4096 + wbase);
      }
    }

    if (kv0 <= rowbase + 31) {            // wave has at least one unmasked col
      // S^T = K Q^T: st[nk][mq]: col = q (mq*16+cl), row = k (nk*16+rg*4+r)
      f32x4 st[4][2];
      #pragma unroll
      for (int i=0;i<4;i++)
        #pragma unroll
        for (int j=0;j<2;j++)
          #pragma unroll
          for (int r=0;r<4;r++) st[i][j][r] = 0.f;

      #pragma unroll
      for (int kk2=0;kk2<2;kk2++){
        s16x8 kf[4];
        #pragma unroll
        for (int nk=0;nk<4;nk++){
          int row = nk*16+cl;
          kf[nk] = *(const s16x8*)&Ks[cur][row*64 + (((kk2*4+rg) ^ (row&7))<<3)];
        }
        #pragma unroll
        for (int nk=0;nk<4;nk++)
          #pragma unroll
          for (int mq=0;mq<2;mq++)
            st[nk][mq] = __builtin_amdgcn_mfma_f32_16x16x32_bf16(kf[nk], qf[mq][kk2], st[nk][mq], 0,0,0);
      }

      const bool full = (kv0 + 63) <= rowbase;   // whole tile unmasked (wave-uniform)
      float mx[2];
      if (full) {
        #pragma unroll
        for (int mq=0;mq<2;mq++){
          float a0 = -1e30f, a1 = -1e30f;
          #pragma unroll
          for (int nk=0;nk<4;nk++){
            #pragma unroll
            for (int r=0;r<4;r++){
              float vv = st[nk][mq][r]*SCL;
              st[nk][mq][r] = vv;
              if (r&1) a1 = fmaxf(a1, vv); else a0 = fmaxf(a0, vv);
            }
          }
          float m0 = fmaxf(a0, a1);
          m0 = fmaxf(m0, __shfl_xor(m0, 16, 64));
          m0 = fmaxf(m0, __shfl_xor(m0, 32, 64));
          mx[mq] = m0;
        }
      } else {
        #pragma unroll
        for (int mq=0;mq<2;mq++){
          int qgr = rowbase + mq*16 + cl;
          float a0 = -1e30f, a1 = -1e30f;
          #pragma unroll
          for (int nk=0;nk<4;nk++){
            #pragma unroll
            for (int r=0;r<4;r++){
              float vv = st[nk][mq][r]*SCL;
              int kgi = kv0 + nk*16 + rg4 + r;
              vv = (kgi<=qgr) ? vv : -1e30f;
              st[nk][mq][r] = vv;
              if (r&1) a1 = fmaxf(a1, vv); else a0 = fmaxf(a0, vv);
            }
          }
          float m0 = fmaxf(a0, a1);
          m0 = fmaxf(m0, __shfl_xor(m0, 16, 64));
          m0 = fmaxf(m0, __shfl_xor(m0, 32, 64));
          mx[mq] = m0;
        }
      }

      // T13 defer-max: only rescale when tile max grows past mrun+8
      bool need = (mx[0] > mrun[0] + 8.f) || (mx[1] > mrun[1] + 8.f);
      if (__any(need)) {
        #pragma unroll
        for (int mq=0;mq<2;mq++){
          float mn = fmaxf(mrun[mq], mx[mq]);
          float corr = __builtin_amdgcn_exp2f(mrun[mq] - mn);
          mrun[mq] = mn;
          lrun[mq] *= corr;
          #pragma unroll
          for (int r=0;r<4;r++){
            float cb = __shfl(corr, (lane & 48) | (rg4 + r), 64);
            #pragma unroll
            for (int nj=0;nj<4;nj++) oacc[mq][nj][r] *= cb;
          }
        }
      }

      // P = exp2(S - m); accumulate PER-LANE partial row-sum (reduced in epilogue);
      // pack to LDS (b64 per (mq,nk))
      #pragma unroll
      for (int mq=0;mq<2;mq++){
        float rs = 0.f;
        #pragma unroll
        for (int nk=0;nk<4;nk++){
          #pragma unroll
          for (int r=0;r<4;r++){
            float pv = __builtin_amdgcn_exp2f(st[nk][mq][r] - mrun[mq]);
            st[nk][mq][r] = pv; rs += pv;
          }
        }
        lrun[mq] += rs;

        int q = mq*16 + cl;
        #pragma unroll
        for (int nk=0;nk<4;nk++){
          uint32_t pk01, pk23;
          asm("v_cvt_pk_bf16_f32 %0, %1, %2" : "=v"(pk01) : "v"(st[nk][mq][0]), "v"(st[nk][mq][1]));
          asm("v_cvt_pk_bf16_f32 %0, %1, %2" : "=v"(pk23) : "v"(st[nk][mq][2]), "v"(st[nk][mq][3]));
          int k0e = nk*16 + rg4;          // 4-aligned, 4 consecutive k
          int ch = k0e>>3, el = k0e&7;    // el = 0 or 4
          char* p = (char*)PsW + q*128 + ((ch ^ (q&7))<<4) + el*2;
          *(uint2*)p = make_uint2(pk01, pk23);
        }
      }

      // PV: O += P @ V  (swizzled reads)
      #pragma unroll
      for (int kk2=0;kk2<2;kk2++){
        s16x8 pf[2], vf[4];
        #pragma unroll
        for (int mi=0;mi<2;mi++){
          int row = mi*16+cl;
          pf[mi] = *(const s16x8*)&PsW[row*64 + (((kk2*4+rg) ^ (row&7))<<3)];
        }
        #pragma unroll
        for (int nj=0;nj<4;nj++){
          int row = nj*16+cl;
          vf[nj] = *(const s16x8*)&Vs[cur][row*64 + (((kk2*4+rg) ^ (row&7))<<3)];
        }
        #pragma unroll
        for (int mi=0;mi<2;mi++)
          #pragma unroll
          for (int nj=0;nj<4;nj++)
            oacc[mi][nj] = __builtin_amdgcn_mfma_f32_16x16x32_bf16(pf[mi], vf[nj], oacc[mi][nj], 0,0,0);
      }
    }

    __syncthreads();   // drains the prefetch (vmcnt 0) + P-region reuse safety
  }

  // epilogue: reduce l across rg groups, then redistribute to C-layout rows.
  // SCRAMBLED reference layout: o[b][h*128 + (q>>4)][(q&15)*64 + d]
  #pragma unroll
  for (int mi=0;mi<2;mi++){
    float lsum = lrun[mi];
    lsum += __shfl_xor(lsum, 16, 64);
    lsum += __shfl_xor(lsum, 32, 64);
    #pragma unroll
    for (int r=0;r<4;r++){
      float lb = __shfl(lsum, (lane & 48) | (rg4 + r), 64);
      float linv = 1.f / lb;
      int row = rowbase + mi*16 + rg4 + r;
      int sp = h*128 + (row>>4);
      int epb = (row&15)*64;
      #pragma unroll
      for (int nj=0;nj<4;nj++)
        o[((size_t)b*SS + sp)*EMB + epb + nj*16 + cl] = f2bf(oacc[mi][nj][r]*linv);
    }
  }
}

// ---------------- launch ----------------
extern "C" void kernel_launch(void* const* d_in, const int* in_sizes, int n_in,
                              void* d_out, int out_size, void* d_ws, size_t ws_size,
                              hipStream_t stream)
{
  const float* x  = (const float*)d_in[0];
  const float* Wq = (const float*)d_in[1];
  const float* Wk = (const float*)d_in[2];
  const float* Wv = (const float*)d_in[3];
  const float* Wp = (const float*)d_in[4];
  const float* bp = (const float*)d_in[5];
  float* out = (float*)d_out;

  char* ws = (char*)d_ws;
  const size_t XE = (size_t)MR*EMB*2;      // 16MB
  const size_t WE = (size_t)EMB*EMB*2;     // 2MB
  u16* xb  = (u16*)ws; ws += XE;           // x bf16; reused as attn-out after GEMM0
  u16* wqb = (u16*)ws; ws += WE;           // wq/wk/wv/wp CONTIGUOUS
  u16* wkb = (u16*)ws; ws += WE;
  u16* wvb = (u16*)ws; ws += WE;
  u16* wpb = (u16*)ws; ws += WE;
  u16* qb  = (u16*)ws; ws += XE;
  u16* kb  = (u16*)ws; ws += XE;
  u16* vtb = (u16*)ws; ws += XE;           // V transposed [bh][d][s], written by GEMM0
  float2* tab = (float2*)ws; ws += (size_t)SS*32*sizeof(float2);
  u16* ob  = xb;                           // alias: x dead after GEMM0
  (void)wkb; (void)wvb;

  // one prep launch: x cvt (2M thr) + weights cvt (1M thr) + tables (64K thr)
  k_prep<<<12544, 256, 0, stream>>>(x, Wq, Wk, Wv, Wp, xb, wqb, tab);

  dim3 g1(MR/128, 3*EMB/128);
  k_gemm<0><<<g1, 256, 0, stream>>>(xb, wqb, qb, kb, vtb, nullptr, nullptr, tab);

  k_attn<<<dim3(BB*NHEADS, SS/128), 256, 0, stream>>>(qb, kb, vtb, ob);

  dim3 g2(MR/128, EMB/128);
  k_gemm<1><<<g2, 256, 0, stream>>>(ob, wpb, nullptr, nullptr, nullptr, bp, out, nullptr);
}